// Round 2
// baseline (2534.983 us; speedup 1.0000x reference)
//
#include <hip/hip_runtime.h>
#include <hip/hip_bf16.h>
#include <math.h>

#define LDIM 384
#define CDIM 128
#define HN 4
#define DH 32
#define LL (LDIM*LDIM)
#define NCHUNK 8
#define NPER (LDIM/NCHUNK)

// ---------------- LN row stats: stats[p] = (mean, rstd) of src[src_row(p)] ----------------
__global__ __launch_bounds__(256) void stats_kernel(const float* __restrict__ src,
    float2* __restrict__ stats, int trans)
{
    int p = (blockIdx.x << 2) + (threadIdx.x >> 6);
    int lane = threadIdx.x & 63;
    int row = trans ? ((p % LDIM) * LDIM + p / LDIM) : p;
    float2 v = *(const float2*)(src + (size_t)row * CDIM + (lane << 1));
    float s  = v.x + v.y;
    float ss = v.x*v.x + v.y*v.y;
    #pragma unroll
    for (int off = 32; off; off >>= 1) { s += __shfl_xor(s, off, 64); ss += __shfl_xor(ss, off, 64); }
    if (lane == 0) {
        float mean = s * (1.0f/CDIM);
        float var  = ss * (1.0f/CDIM) - mean*mean;
        stats[p] = make_float2(mean, rsqrtf(var + 1e-5f));
    }
}

// ---------------- bias-attention: battn[h,i,j] = LN(rbf[src(i,j)]) . wb[:,h] ----------------
__global__ __launch_bounds__(256) void battn_kernel(const float* __restrict__ rbf,
    float* __restrict__ battn, const float* __restrict__ lnw, const float* __restrict__ lnb,
    const float* __restrict__ wb, int trans)
{
    int p = (blockIdx.x << 2) + (threadIdx.x >> 6);
    int lane = threadIdx.x & 63;
    int i = p / LDIM, j = p % LDIM;
    int srow = trans ? (j * LDIM + i) : p;
    float2 v = *(const float2*)(rbf + (size_t)srow * CDIM + (lane << 1));
    float s = v.x + v.y, ss = v.x*v.x + v.y*v.y;
    #pragma unroll
    for (int off = 32; off; off >>= 1) { s += __shfl_xor(s, off, 64); ss += __shfl_xor(ss, off, 64); }
    float mean = s*(1.f/CDIM), var = ss*(1.f/CDIM) - mean*mean, rstd = rsqrtf(var + 1e-5f);
    float x0 = (v.x - mean)*rstd*lnw[lane<<1]     + lnb[lane<<1];
    float x1 = (v.y - mean)*rstd*lnw[(lane<<1)+1] + lnb[(lane<<1)+1];
    int c0 = (lane<<1)*HN, c1 = ((lane<<1)+1)*HN;
    float a0 = x0*wb[c0+0] + x1*wb[c1+0];
    float a1 = x0*wb[c0+1] + x1*wb[c1+1];
    float a2 = x0*wb[c0+2] + x1*wb[c1+2];
    float a3 = x0*wb[c0+3] + x1*wb[c1+3];
    #pragma unroll
    for (int off = 32; off; off >>= 1) {
        a0 += __shfl_xor(a0, off, 64); a1 += __shfl_xor(a1, off, 64);
        a2 += __shfl_xor(a2, off, 64); a3 += __shfl_xor(a3, off, 64);
    }
    if (lane == 0) {
        battn[((size_t)0*LDIM + i)*LDIM + j] = a0;
        battn[((size_t)1*LDIM + i)*LDIM + j] = a1;
        battn[((size_t)2*LDIM + i)*LDIM + j] = a2;
        battn[((size_t)3*LDIM + i)*LDIM + j] = a3;
    }
}

// ------- generic fp32 GEMM: C = epi(alpha*(LN?(A)@W) + bias) [*mul] [+res], 64x64 tile -------
// ACT: 0 none, 1 relu, 2 sigmoid. LNA: apply LayerNorm to A rows during staging (needs stats).
// a_trans/res_trans/out_trans remap frame row p=(n*L+i) -> (i*L+n) for reads/writes.
template<int ACT, int LNA>
__global__ __launch_bounds__(256) void gemm_kernel(
    const float* __restrict__ A, const float* __restrict__ W,
    const float* __restrict__ bias, const float* __restrict__ mul,
    const float* __restrict__ res, float* __restrict__ C,
    const float2* __restrict__ stats, const float* __restrict__ lnw, const float* __restrict__ lnb,
    int N, int K, float alpha, int a_trans, int res_trans, int out_trans)
{
    __shared__ float As[16][64];   // [k][m]
    __shared__ float Ws[16][64];   // [k][n]
    int t = threadIdx.x;
    int m0 = blockIdx.x << 6;
    int n0 = blockIdx.y << 6;
    int tm = t >> 4, tn = t & 15;
    int am = t >> 2, akq = (t & 3) << 2;       // A staging: row am, k-offset akq
    int wkk = t >> 4, wn = (t & 15) << 2;      // W staging
    int amrow = m0 + am;
    size_t arow = a_trans ? ((size_t)(amrow % LDIM) * LDIM + amrow / LDIM) : (size_t)amrow;
    float2 st = LNA ? stats[amrow] : make_float2(0.f, 1.f);
    float acc[4][4] = {};
    for (int k0 = 0; k0 < K; k0 += 16) {
        const float* ap = A + arow * K + k0 + akq;
        if (LNA) {
            float4 a4 = *(const float4*)ap;
            As[akq+0][am] = (a4.x - st.x) * st.y * lnw[k0+akq+0] + lnb[k0+akq+0];
            As[akq+1][am] = (a4.y - st.x) * st.y * lnw[k0+akq+1] + lnb[k0+akq+1];
            As[akq+2][am] = (a4.z - st.x) * st.y * lnw[k0+akq+2] + lnb[k0+akq+2];
            As[akq+3][am] = (a4.w - st.x) * st.y * lnw[k0+akq+3] + lnb[k0+akq+3];
        } else if (k0 + 16 <= K) {
            float4 a4 = *(const float4*)ap;
            As[akq+0][am] = a4.x; As[akq+1][am] = a4.y;
            As[akq+2][am] = a4.z; As[akq+3][am] = a4.w;
        } else {
            #pragma unroll
            for (int jj = 0; jj < 4; jj++)
                As[akq+jj][am] = (k0 + akq + jj < K) ? ap[jj] : 0.f;
        }
        float4 w4 = make_float4(0.f, 0.f, 0.f, 0.f);
        if (k0 + wkk < K) w4 = *(const float4*)(W + (size_t)(k0 + wkk) * N + n0 + wn);
        *(float4*)&Ws[wkk][wn] = w4;
        __syncthreads();
        #pragma unroll
        for (int kk = 0; kk < 16; kk++) {
            float4 a = *(const float4*)&As[kk][tm << 2];
            float4 b = *(const float4*)&Ws[kk][tn << 2];
            acc[0][0] += a.x*b.x; acc[0][1] += a.x*b.y; acc[0][2] += a.x*b.z; acc[0][3] += a.x*b.w;
            acc[1][0] += a.y*b.x; acc[1][1] += a.y*b.y; acc[1][2] += a.y*b.z; acc[1][3] += a.y*b.w;
            acc[2][0] += a.z*b.x; acc[2][1] += a.z*b.y; acc[2][2] += a.z*b.z; acc[2][3] += a.z*b.w;
            acc[3][0] += a.w*b.x; acc[3][1] += a.w*b.y; acc[3][2] += a.w*b.z; acc[3][3] += a.w*b.w;
        }
        __syncthreads();
    }
    #pragma unroll
    for (int i = 0; i < 4; i++) {
        int m = m0 + (tm << 2) + i;
        size_t orow = out_trans ? ((size_t)(m % LDIM) * LDIM + m / LDIM) : (size_t)m;
        size_t rrow = res_trans ? ((size_t)(m % LDIM) * LDIM + m / LDIM) : (size_t)m;
        int n = n0 + (tn << 2);
        float4 v;
        v.x = acc[i][0] * alpha; v.y = acc[i][1] * alpha;
        v.z = acc[i][2] * alpha; v.w = acc[i][3] * alpha;
        if (bias) { v.x += bias[n]; v.y += bias[n+1]; v.z += bias[n+2]; v.w += bias[n+3]; }
        if (ACT == 1) {
            v.x = fmaxf(v.x, 0.f); v.y = fmaxf(v.y, 0.f);
            v.z = fmaxf(v.z, 0.f); v.w = fmaxf(v.w, 0.f);
        } else if (ACT == 2) {
            v.x = 1.f/(1.f+__expf(-v.x)); v.y = 1.f/(1.f+__expf(-v.y));
            v.z = 1.f/(1.f+__expf(-v.z)); v.w = 1.f/(1.f+__expf(-v.w));
        }
        if (mul) {
            float4 mm = *(const float4*)(mul + (size_t)m * N + n);
            v.x *= mm.x; v.y *= mm.y; v.z *= mm.z; v.w *= mm.w;
        }
        if (res) {
            float4 rr = *(const float4*)(res + rrow * N + n);
            v.x += rr.x; v.y += rr.y; v.z += rr.z; v.w += rr.w;
        }
        *(float4*)(C + orow * N + n) = v;
    }
}

// ------------- tied attention scores: partial[c,h,i,j] = sum_{n in chunk} sum_k q.k -------------
__global__ __launch_bounds__(64) void score_kernel(
    const float* __restrict__ Q, const float* __restrict__ Kmat, float* __restrict__ partial)
{
    __shared__ float qS[32][32];  // [k][i]
    __shared__ float kS[32][32];  // [k][j]
    int bi = blockIdx.x / (LDIM/32), bj = blockIdx.x % (LDIM/32);
    int h = blockIdx.y, chunk = blockIdx.z;
    int i0 = bi << 5, j0 = bj << 5;
    int l = threadIdx.x;
    int sr = l & 31;            // staged row
    int skq = (l >> 5) << 4;    // staged k offset (0 or 16)
    int li = (l & 7) << 2, lj = (l >> 3) << 2;
    float acc[4][4] = {};
    for (int n = chunk * NPER; n < (chunk + 1) * NPER; n++) {
        const float* qp = Q    + ((size_t)n*LDIM + i0 + sr)*CDIM + h*DH + skq;
        const float* kp = Kmat + ((size_t)n*LDIM + j0 + sr)*CDIM + h*DH + skq;
        float4 qa = *(const float4*)qp,     qb2 = *(const float4*)(qp+4),
               qc = *(const float4*)(qp+8), qd = *(const float4*)(qp+12);
        float4 ka = *(const float4*)kp,     kb2 = *(const float4*)(kp+4),
               kc = *(const float4*)(kp+8), kd = *(const float4*)(kp+12);
        qS[skq+ 0][sr]=qa.x;  qS[skq+ 1][sr]=qa.y;  qS[skq+ 2][sr]=qa.z;  qS[skq+ 3][sr]=qa.w;
        qS[skq+ 4][sr]=qb2.x; qS[skq+ 5][sr]=qb2.y; qS[skq+ 6][sr]=qb2.z; qS[skq+ 7][sr]=qb2.w;
        qS[skq+ 8][sr]=qc.x;  qS[skq+ 9][sr]=qc.y;  qS[skq+10][sr]=qc.z;  qS[skq+11][sr]=qc.w;
        qS[skq+12][sr]=qd.x;  qS[skq+13][sr]=qd.y;  qS[skq+14][sr]=qd.z;  qS[skq+15][sr]=qd.w;
        kS[skq+ 0][sr]=ka.x;  kS[skq+ 1][sr]=ka.y;  kS[skq+ 2][sr]=ka.z;  kS[skq+ 3][sr]=ka.w;
        kS[skq+ 4][sr]=kb2.x; kS[skq+ 5][sr]=kb2.y; kS[skq+ 6][sr]=kb2.z; kS[skq+ 7][sr]=kb2.w;
        kS[skq+ 8][sr]=kc.x;  kS[skq+ 9][sr]=kc.y;  kS[skq+10][sr]=kc.z;  kS[skq+11][sr]=kc.w;
        kS[skq+12][sr]=kd.x;  kS[skq+13][sr]=kd.y;  kS[skq+14][sr]=kd.z;  kS[skq+15][sr]=kd.w;
        __syncthreads();
        #pragma unroll
        for (int kk = 0; kk < 32; kk++) {
            float4 a = *(const float4*)&qS[kk][li];
            float4 b = *(const float4*)&kS[kk][lj];
            acc[0][0] += a.x*b.x; acc[0][1] += a.x*b.y; acc[0][2] += a.x*b.z; acc[0][3] += a.x*b.w;
            acc[1][0] += a.y*b.x; acc[1][1] += a.y*b.y; acc[1][2] += a.y*b.z; acc[1][3] += a.y*b.w;
            acc[2][0] += a.z*b.x; acc[2][1] += a.z*b.y; acc[2][2] += a.z*b.z; acc[2][3] += a.z*b.w;
            acc[3][0] += a.w*b.x; acc[3][1] += a.w*b.y; acc[3][2] += a.w*b.z; acc[3][3] += a.w*b.w;
        }
        __syncthreads();
    }
    #pragma unroll
    for (int ii = 0; ii < 4; ii++) {
        *(float4*)(partial + ((size_t)(chunk*HN + h)*LDIM + i0 + li + ii)*LDIM + j0 + lj) =
            make_float4(acc[ii][0], acc[ii][1], acc[ii][2], acc[ii][3]);
    }
}

// ---------------- softmax over j with chunk-reduce + bias add ----------------
__global__ __launch_bounds__(64) void softmax_kernel(
    const float* __restrict__ partial, const float* __restrict__ battn, float* __restrict__ attn)
{
    int hi = blockIdx.x;  // h*L + i
    int l = threadIdx.x;
    float s[6];
    #pragma unroll
    for (int u = 0; u < 6; u++) {
        size_t idx = (size_t)hi * LDIM + l + (u << 6);
        float v = battn[idx];
        #pragma unroll
        for (int c = 0; c < NCHUNK; c++) v += partial[(size_t)c * HN * LL + idx];
        s[u] = v;
    }
    float m = s[0];
    #pragma unroll
    for (int u = 1; u < 6; u++) m = fmaxf(m, s[u]);
    #pragma unroll
    for (int off = 32; off; off >>= 1) m = fmaxf(m, __shfl_xor(m, off, 64));
    float sum = 0.f;
    #pragma unroll
    for (int u = 0; u < 6; u++) { s[u] = __expf(s[u] - m); sum += s[u]; }
    #pragma unroll
    for (int off = 32; off; off >>= 1) sum += __shfl_xor(sum, off, 64);
    float inv = 1.f / sum;
    #pragma unroll
    for (int u = 0; u < 6; u++) attn[(size_t)hi * LDIM + l + (u << 6)] = s[u] * inv;
}

// ---------------- PV: out[n,i,hd] = sum_j attn[h,i,j] * v[n,j,hd] ----------------
__global__ __launch_bounds__(256) void pv_kernel(
    const float* __restrict__ attn, const float* __restrict__ V, float* __restrict__ out)
{
    __shared__ float aS[HN][32][32];  // [h][j][i]
    __shared__ float vS[32][132];     // [j][hd] padded
    int i0 = blockIdx.x << 5;
    int n  = blockIdx.y;
    int t = threadIdx.x;
    int w = t >> 6, l = t & 63;      // wave w handles head h=w
    int li = (l & 7) << 2, ld = (l >> 3) << 2;
    int aii = l & 31, ajq = (l >> 5) << 4;
    int vjj = t >> 3, vcq = (t & 7) << 4;
    float acc[4][4] = {};
    for (int j0 = 0; j0 < LDIM; j0 += 32) {
        const float* ap = attn + ((size_t)w*LDIM + i0 + aii)*LDIM + j0 + ajq;
        float4 a0 = *(const float4*)ap,     a1 = *(const float4*)(ap+4),
               a2 = *(const float4*)(ap+8), a3 = *(const float4*)(ap+12);
        aS[w][ajq+ 0][aii]=a0.x; aS[w][ajq+ 1][aii]=a0.y; aS[w][ajq+ 2][aii]=a0.z; aS[w][ajq+ 3][aii]=a0.w;
        aS[w][ajq+ 4][aii]=a1.x; aS[w][ajq+ 5][aii]=a1.y; aS[w][ajq+ 6][aii]=a1.z; aS[w][ajq+ 7][aii]=a1.w;
        aS[w][ajq+ 8][aii]=a2.x; aS[w][ajq+ 9][aii]=a2.y; aS[w][ajq+10][aii]=a2.z; aS[w][ajq+11][aii]=a2.w;
        aS[w][ajq+12][aii]=a3.x; aS[w][ajq+13][aii]=a3.y; aS[w][ajq+14][aii]=a3.z; aS[w][ajq+15][aii]=a3.w;
        const float* vp = V + ((size_t)n*LDIM + j0 + vjj)*CDIM + vcq;
        float4 v0 = *(const float4*)vp,     v1 = *(const float4*)(vp+4),
               v2 = *(const float4*)(vp+8), v3 = *(const float4*)(vp+12);
        *(float4*)&vS[vjj][vcq+ 0] = v0;
        *(float4*)&vS[vjj][vcq+ 4] = v1;
        *(float4*)&vS[vjj][vcq+ 8] = v2;
        *(float4*)&vS[vjj][vcq+12] = v3;
        __syncthreads();
        #pragma unroll
        for (int jj = 0; jj < 32; jj++) {
            float4 a = *(const float4*)&aS[w][jj][li];
            float4 b = *(const float4*)&vS[jj][(w << 5) + ld];
            acc[0][0] += a.x*b.x; acc[0][1] += a.x*b.y; acc[0][2] += a.x*b.z; acc[0][3] += a.x*b.w;
            acc[1][0] += a.y*b.x; acc[1][1] += a.y*b.y; acc[1][2] += a.y*b.z; acc[1][3] += a.y*b.w;
            acc[2][0] += a.z*b.x; acc[2][1] += a.z*b.y; acc[2][2] += a.z*b.z; acc[2][3] += a.z*b.w;
            acc[3][0] += a.w*b.x; acc[3][1] += a.w*b.y; acc[3][2] += a.w*b.z; acc[3][3] += a.w*b.w;
        }
        __syncthreads();
    }
    #pragma unroll
    for (int ii = 0; ii < 4; ii++) {
        *(float4*)(out + ((size_t)n*LDIM + i0 + li + ii)*CDIM + (w << 5) + ld) =
            make_float4(acc[ii][0], acc[ii][1], acc[ii][2], acc[ii][3]);
    }
}

extern "C" void kernel_launch(void* const* d_in, const int* in_sizes, int n_in,
                              void* d_out, int out_size, void* d_ws, size_t ws_size,
                              hipStream_t stream)
{
    const float* pair     = (const float*)d_in[0];
    const float* rbf_feat = (const float*)d_in[1];
    const float* emb_w    = (const float*)d_in[2];
    const float* emb_b    = (const float*)d_in[3];
    const float* proj_w   = (const float*)d_in[4];
    const float* proj_b   = (const float*)d_in[5];
    const float* ff_ln_w  = (const float*)d_in[30];
    const float* ff_ln_b  = (const float*)d_in[31];
    const float* ff_w1    = (const float*)d_in[32];
    const float* ff_b1    = (const float*)d_in[33];
    const float* ff_w2    = (const float*)d_in[34];
    const float* ff_b2    = (const float*)d_in[35];
    float* out = (float*)d_out;

    // workspace layout (floats) — total 44,531,712 floats = 178.1 MB
    float*  A        = (float*)d_ws;                    // LL*128 (also FFN hidden with B)
    float*  Bf       = A      + (size_t)LL*CDIM;        // LL*128 (contiguous after A)
    float*  partialb = Bf     + (size_t)LL*CDIM;        // NCHUNK*HN*LL
    float*  battn_r  = partialb + (size_t)NCHUNK*HN*LL; // HN*LL
    float*  battn_c  = battn_r  + (size_t)HN*LL;        // HN*LL
    float*  attnb    = battn_c  + (size_t)HN*LL;        // HN*LL
    float2* statsb   = (float2*)(attnb + (size_t)HN*LL); // LL float2

    size_t need_bytes = ((size_t)2*LL*CDIM + (size_t)NCHUNK*HN*LL + (size_t)3*HN*LL + (size_t)2*LL) * 4;
    if (ws_size < need_bytes) return;  // controlled failure signal instead of OOB crash

    const float SCALE = 0.17677669529663687f;  // 32^-0.5
    dim3 g128(LL/64, 2), g256(LL/64, 4);

    // rbf = relu(rbf_feat@emb_w+emb_b)@proj_w + proj_b  (transient in A, B)
    gemm_kernel<1,0><<<g128, 256, 0, stream>>>(rbf_feat, emb_w, emb_b, nullptr, nullptr, A,
        nullptr, nullptr, nullptr, 128, 36, 1.f, 0, 0, 0);
    gemm_kernel<0,0><<<g128, 256, 0, stream>>>(A, proj_w, proj_b, nullptr, nullptr, Bf,
        nullptr, nullptr, nullptr, 128, 128, 1.f, 0, 0, 0);
    // both frames' pairwise bias up front (rbf buffer then dies)
    battn_kernel<<<LL/4, 256, 0, stream>>>(Bf, battn_r, (const float*)d_in[8],  (const float*)d_in[9],  (const float*)d_in[13], 1);
    battn_kernel<<<LL/4, 256, 0, stream>>>(Bf, battn_c, (const float*)d_in[20], (const float*)d_in[21], (const float*)d_in[25], 0);

    for (int pass = 0; pass < 2; pass++) {
        const float* const* wp = (const float* const*)(d_in + (pass ? 18 : 6));
        int trans = pass ? 0 : 1;                 // row pass works in transposed frame
        const float* P = pass ? (const float*)out : pair;
        const float* battnb = pass ? battn_c : battn_r;
        // wp: 0 lnp_w 1 lnp_b 2 lnb_w 3 lnb_b 4 wq 5 wk 6 wv 7 wb 8 wg 9 bg 10 wo 11 bo
        stats_kernel<<<LL/4, 256, 0, stream>>>(P, statsb, trans);
        gemm_kernel<0,1><<<g128, 256, 0, stream>>>(P, wp[4], nullptr, nullptr, nullptr, A,
            statsb, wp[0], wp[1], 128, 128, SCALE, trans, 0, 0);
        gemm_kernel<0,1><<<g128, 256, 0, stream>>>(P, wp[5], nullptr, nullptr, nullptr, Bf,
            statsb, wp[0], wp[1], 128, 128, 1.f/LDIM, trans, 0, 0);
        score_kernel<<<dim3((LDIM/32)*(LDIM/32), HN, NCHUNK), 64, 0, stream>>>(A, Bf, partialb);
        softmax_kernel<<<HN*LDIM, 64, 0, stream>>>(partialb, battnb, attnb);
        // v into A (q dead), pv-out into B (k dead)
        gemm_kernel<0,1><<<g128, 256, 0, stream>>>(P, wp[6], nullptr, nullptr, nullptr, A,
            statsb, wp[0], wp[1], 128, 128, 1.f, trans, 0, 0);
        pv_kernel<<<dim3(LDIM/32, LDIM), 256, 0, stream>>>(attnb, A, Bf);
        // z = sigmoid(LN(P)@wg+bg) * pv_out   (in-place on B)
        gemm_kernel<2,1><<<g128, 256, 0, stream>>>(P, wp[8], wp[9], Bf, nullptr, Bf,
            statsb, wp[0], wp[1], 128, 128, 1.f, trans, 0, 0);
        // pair_out = residual + z@wo + bo   (transposed IO for row pass)
        gemm_kernel<0,0><<<g128, 256, 0, stream>>>(Bf, wp[10], wp[11], nullptr, P, out,
            nullptr, nullptr, nullptr, 128, 128, 1.f, 0, trans, trans);
    }

    // FFN: out += relu(LN(out)@w1+b1)@w2+b2   (hidden LLx256 spans A..B)
    stats_kernel<<<LL/4, 256, 0, stream>>>(out, statsb, 0);
    gemm_kernel<1,1><<<g256, 256, 0, stream>>>(out, ff_w1, ff_b1, nullptr, nullptr, A,
        statsb, ff_ln_w, ff_ln_b, 256, 128, 1.f, 0, 0, 0);
    gemm_kernel<0,0><<<g128, 256, 0, stream>>>(A, ff_w2, ff_b2, nullptr, out, out,
        nullptr, nullptr, nullptr, 128, 256, 1.f, 0, 0, 0);
}

// Round 3
// 1658.075 us; speedup vs baseline: 1.5289x; 1.5289x over previous
//
#include <hip/hip_runtime.h>
#include <hip/hip_bf16.h>
#include <math.h>

#define LDIM 384
#define CDIM 128
#define HN 4
#define DH 32
#define LL (LDIM*LDIM)
#define NCHUNK 8

typedef __attribute__((ext_vector_type(8))) short bf16x8;
typedef __attribute__((ext_vector_type(4))) float f32x4;

__device__ __forceinline__ ushort f2bf(float x) {
    union { __hip_bfloat16 h; ushort u; } cv;
    cv.h = __float2bfloat16(x);
    return cv.u;
}
__device__ __forceinline__ float bf2f(ushort u) {
    union { unsigned int i; float f; } cv; cv.i = ((unsigned int)u) << 16; return cv.f;
}

// ---------------- LN + bf16 pack: dst[p][c] = bf16(LN(src[src_row(p)])) ----------------
__global__ __launch_bounds__(256) void lnpack_kernel(const float* __restrict__ src,
    ushort* __restrict__ dst, const float* __restrict__ w, const float* __restrict__ b, int trans)
{
    int p = (blockIdx.x << 2) + (threadIdx.x >> 6);
    int lane = threadIdx.x & 63;
    int row = trans ? ((p % LDIM) * LDIM + p / LDIM) : p;
    float2 v = *(const float2*)(src + (size_t)row * CDIM + (lane << 1));
    float s  = v.x + v.y;
    float ss = v.x*v.x + v.y*v.y;
    #pragma unroll
    for (int off = 32; off; off >>= 1) { s += __shfl_xor(s, off, 64); ss += __shfl_xor(ss, off, 64); }
    float mean = s * (1.0f/CDIM);
    float var  = ss * (1.0f/CDIM) - mean*mean;
    float rstd = rsqrtf(var + 1e-5f);
    ushort2 o;
    o.x = f2bf((v.x - mean) * rstd * w[lane<<1]     + b[lane<<1]);
    o.y = f2bf((v.y - mean) * rstd * w[(lane<<1)+1] + b[(lane<<1)+1]);
    *(ushort2*)(dst + (size_t)p * CDIM + (lane << 1)) = o;
}

// ---------------- bias-attention: battn[h,i,j] = LN(rbf[src(i,j)]) . wb[:,h] ----------------
__global__ __launch_bounds__(256) void battn_kernel(const float* __restrict__ rbf,
    float* __restrict__ battn, const float* __restrict__ lnw, const float* __restrict__ lnb,
    const float* __restrict__ wb, int trans)
{
    int p = (blockIdx.x << 2) + (threadIdx.x >> 6);
    int lane = threadIdx.x & 63;
    int i = p / LDIM, j = p % LDIM;
    int srow = trans ? (j * LDIM + i) : p;
    float2 v = *(const float2*)(rbf + (size_t)srow * CDIM + (lane << 1));
    float s = v.x + v.y, ss = v.x*v.x + v.y*v.y;
    #pragma unroll
    for (int off = 32; off; off >>= 1) { s += __shfl_xor(s, off, 64); ss += __shfl_xor(ss, off, 64); }
    float mean = s*(1.f/CDIM), var = ss*(1.f/CDIM) - mean*mean, rstd = rsqrtf(var + 1e-5f);
    float x0 = (v.x - mean)*rstd*lnw[lane<<1]     + lnb[lane<<1];
    float x1 = (v.y - mean)*rstd*lnw[(lane<<1)+1] + lnb[(lane<<1)+1];
    int c0 = (lane<<1)*HN, c1 = ((lane<<1)+1)*HN;
    float a0 = x0*wb[c0+0] + x1*wb[c1+0];
    float a1 = x0*wb[c0+1] + x1*wb[c1+1];
    float a2 = x0*wb[c0+2] + x1*wb[c1+2];
    float a3 = x0*wb[c0+3] + x1*wb[c1+3];
    #pragma unroll
    for (int off = 32; off; off >>= 1) {
        a0 += __shfl_xor(a0, off, 64); a1 += __shfl_xor(a1, off, 64);
        a2 += __shfl_xor(a2, off, 64); a3 += __shfl_xor(a3, off, 64);
    }
    if (lane == 0) {
        battn[((size_t)0*LDIM + i)*LDIM + j] = a0;
        battn[((size_t)1*LDIM + i)*LDIM + j] = a1;
        battn[((size_t)2*LDIM + i)*LDIM + j] = a2;
        battn[((size_t)3*LDIM + i)*LDIM + j] = a3;
    }
}

// ------- MFMA bf16 GEMM: C = epi(alpha*(A@W) + bias) [*mul] [+res], 64x64 tile, 4 waves -------
// ACT: 0 none, 1 relu, 2 sigmoid. ABF: A is bf16 (else fp32, converted).
// OUTMODE: 0 fp32 natural (+res), 1 bf16 natural (*mul opt), 2 bf16 v-transposed [n][c][j],
//          3 fp32 natural/trans (+res w/ rtrans, write w/ otrans).
template<int ACT, int ABF, int OUTMODE>
__global__ __launch_bounds__(256) void mgemm_kernel(
    const void* __restrict__ Ain, const float* __restrict__ W,
    const float* __restrict__ bias, const ushort* __restrict__ mulbf,
    const float* __restrict__ res, void* __restrict__ Cout,
    int N, int K, float alpha, int rtrans, int otrans)
{
    __shared__ ushort As[64][136];   // [m][k], pad => worst 2-way bank conflict
    __shared__ ushort Ws[64][136];   // [n][k]
    int t = threadIdx.x, l = t & 63, wv = t >> 6;
    int m0 = blockIdx.x << 6, n0 = blockIdx.y << 6;
    int wm = (wv >> 1) << 5, wn = (wv & 1) << 5;
    int ar = t >> 2, sk = (t & 3) << 5;      // A staging: row, 32-wide k-chunk
    int wnn = t >> 2, wsk = (t & 3) << 5;    // W staging: col n, k-chunk
    f32x4 acc[2][2] = {};
    for (int k0 = 0; k0 < K; k0 += 128) {
        if (ABF) {
            const ushort* ap = (const ushort*)Ain + (size_t)(m0 + ar) * K + k0 + sk;
            *(int4*)&As[ar][sk]      = *(const int4*)ap;
            *(int4*)&As[ar][sk + 8]  = *(const int4*)(ap + 8);
            *(int4*)&As[ar][sk + 16] = *(const int4*)(ap + 16);
            *(int4*)&As[ar][sk + 24] = *(const int4*)(ap + 24);
        } else {
            const float* ap = (const float*)Ain + (size_t)(m0 + ar) * K + k0 + sk;
            #pragma unroll
            for (int u = 0; u < 32; u += 4) {
                float4 a4;
                if (k0 + sk + u + 3 < K) a4 = *(const float4*)(ap + u);
                else {
                    float t0 = (k0+sk+u+0 < K) ? ap[u+0] : 0.f;
                    float t1 = (k0+sk+u+1 < K) ? ap[u+1] : 0.f;
                    float t2 = (k0+sk+u+2 < K) ? ap[u+2] : 0.f;
                    float t3 = (k0+sk+u+3 < K) ? ap[u+3] : 0.f;
                    a4 = make_float4(t0, t1, t2, t3);
                }
                ushort4 o; o.x=f2bf(a4.x); o.y=f2bf(a4.y); o.z=f2bf(a4.z); o.w=f2bf(a4.w);
                *(ushort4*)&As[ar][sk + u] = o;
            }
        }
        #pragma unroll
        for (int u = 0; u < 32; u += 4) {
            ushort4 o;
            float w0 = (k0+wsk+u+0 < K) ? W[(size_t)(k0+wsk+u+0)*N + n0 + wnn] : 0.f;
            float w1 = (k0+wsk+u+1 < K) ? W[(size_t)(k0+wsk+u+1)*N + n0 + wnn] : 0.f;
            float w2 = (k0+wsk+u+2 < K) ? W[(size_t)(k0+wsk+u+2)*N + n0 + wnn] : 0.f;
            float w3 = (k0+wsk+u+3 < K) ? W[(size_t)(k0+wsk+u+3)*N + n0 + wnn] : 0.f;
            o.x=f2bf(w0); o.y=f2bf(w1); o.z=f2bf(w2); o.w=f2bf(w3);
            *(ushort4*)&Ws[wnn][wsk + u] = o;
        }
        __syncthreads();
        #pragma unroll
        for (int ks = 0; ks < 4; ks++) {
            int ko = (ks << 5) + ((l >> 4) << 3);
            bf16x8 a0 = *(const bf16x8*)&As[wm + (l & 15)][ko];
            bf16x8 a1 = *(const bf16x8*)&As[wm + 16 + (l & 15)][ko];
            bf16x8 b0 = *(const bf16x8*)&Ws[wn + (l & 15)][ko];
            bf16x8 b1 = *(const bf16x8*)&Ws[wn + 16 + (l & 15)][ko];
            acc[0][0] = __builtin_amdgcn_mfma_f32_16x16x32_bf16(a0, b0, acc[0][0], 0, 0, 0);
            acc[0][1] = __builtin_amdgcn_mfma_f32_16x16x32_bf16(a0, b1, acc[0][1], 0, 0, 0);
            acc[1][0] = __builtin_amdgcn_mfma_f32_16x16x32_bf16(a1, b0, acc[1][0], 0, 0, 0);
            acc[1][1] = __builtin_amdgcn_mfma_f32_16x16x32_bf16(a1, b1, acc[1][1], 0, 0, 0);
        }
        __syncthreads();
    }
    #pragma unroll
    for (int mf = 0; mf < 2; mf++)
    #pragma unroll
    for (int nf = 0; nf < 2; nf++) {
        int col  = n0 + wn + (nf << 4) + (l & 15);
        int row0 = m0 + wm + (mf << 4) + ((l >> 4) << 2);
        float bb = bias ? bias[col] : 0.f;
        ushort4 pk;
        #pragma unroll
        for (int r = 0; r < 4; r++) {
            int row = row0 + r;
            float v = acc[mf][nf][r] * alpha + bb;
            if (ACT == 1) v = fmaxf(v, 0.f);
            if (ACT == 2) v = 1.f / (1.f + __expf(-v));
            if (mulbf) v *= bf2f(mulbf[(size_t)row * N + col]);
            if (OUTMODE == 0) {
                float o = v + (res ? res[(size_t)row * N + col] : 0.f);
                ((float*)Cout)[(size_t)row * N + col] = o;
            } else if (OUTMODE == 1) {
                ((ushort*)Cout)[(size_t)row * N + col] = f2bf(v);
            } else if (OUTMODE == 2) {
                ((ushort*)&pk)[r] = f2bf(v);
            } else {
                size_t orow = otrans ? ((size_t)(row % LDIM) * LDIM + row / LDIM) : (size_t)row;
                size_t rrow = rtrans ? ((size_t)(row % LDIM) * LDIM + row / LDIM) : (size_t)row;
                float o = v + (res ? res[rrow * N + col] : 0.f);
                ((float*)Cout)[orow * N + col] = o;
            }
        }
        if (OUTMODE == 2) {
            int n = row0 / LDIM, j = row0 % LDIM;   // 64-row tiles never cross n
            *(ushort4*)&((ushort*)Cout)[((size_t)n * CDIM + col) * LDIM + j] = pk;
        }
    }
}

// ------- tied scores via MFMA: partial[c,h,i,j] = sum_{kdim in chunk} Q.K (kdim = n*32+kc) -------
__global__ __launch_bounds__(256) void score_mfma(const ushort* __restrict__ Q,
    const ushort* __restrict__ Kb, float* __restrict__ partial)
{
    __shared__ ushort As[64][136];
    __shared__ ushort Bs[64][136];
    int t = threadIdx.x, l = t & 63, wv = t >> 6;
    int bi = blockIdx.x / 6, bj = blockIdx.x % 6;
    int h = blockIdx.y, cz = blockIdx.z;
    int i0 = bi << 6, j0 = bj << 6;
    int wm = (wv >> 1) << 5, wn = (wv & 1) << 5;
    int ar = t >> 2, s = t & 3, sk = s << 5;
    f32x4 acc[2][2] = {};
    for (int it = 0; it < 12; it++) {
        int n = cz * 48 + (it << 2) + s;
        const ushort* qp = Q  + ((size_t)n * LDIM + i0 + ar) * CDIM + h * DH;
        const ushort* kp = Kb + ((size_t)n * LDIM + j0 + ar) * CDIM + h * DH;
        *(int4*)&As[ar][sk]      = *(const int4*)qp;
        *(int4*)&As[ar][sk + 8]  = *(const int4*)(qp + 8);
        *(int4*)&As[ar][sk + 16] = *(const int4*)(qp + 16);
        *(int4*)&As[ar][sk + 24] = *(const int4*)(qp + 24);
        *(int4*)&Bs[ar][sk]      = *(const int4*)kp;
        *(int4*)&Bs[ar][sk + 8]  = *(const int4*)(kp + 8);
        *(int4*)&Bs[ar][sk + 16] = *(const int4*)(kp + 16);
        *(int4*)&Bs[ar][sk + 24] = *(const int4*)(kp + 24);
        __syncthreads();
        #pragma unroll
        for (int ks = 0; ks < 4; ks++) {
            int ko = (ks << 5) + ((l >> 4) << 3);
            bf16x8 a0 = *(const bf16x8*)&As[wm + (l & 15)][ko];
            bf16x8 a1 = *(const bf16x8*)&As[wm + 16 + (l & 15)][ko];
            bf16x8 b0 = *(const bf16x8*)&Bs[wn + (l & 15)][ko];
            bf16x8 b1 = *(const bf16x8*)&Bs[wn + 16 + (l & 15)][ko];
            acc[0][0] = __builtin_amdgcn_mfma_f32_16x16x32_bf16(a0, b0, acc[0][0], 0, 0, 0);
            acc[0][1] = __builtin_amdgcn_mfma_f32_16x16x32_bf16(a0, b1, acc[0][1], 0, 0, 0);
            acc[1][0] = __builtin_amdgcn_mfma_f32_16x16x32_bf16(a1, b0, acc[1][0], 0, 0, 0);
            acc[1][1] = __builtin_amdgcn_mfma_f32_16x16x32_bf16(a1, b1, acc[1][1], 0, 0, 0);
        }
        __syncthreads();
    }
    #pragma unroll
    for (int mf = 0; mf < 2; mf++)
    #pragma unroll
    for (int nf = 0; nf < 2; nf++) {
        int j = j0 + wn + (nf << 4) + (l & 15);
        int ib = i0 + wm + (mf << 4) + ((l >> 4) << 2);
        #pragma unroll
        for (int r = 0; r < 4; r++)
            partial[((size_t)(cz*HN + h)*LDIM + ib + r)*LDIM + j] = acc[mf][nf][r];
    }
}

// ---------------- softmax over j with chunk-reduce + bias add -> bf16 attn ----------------
__global__ __launch_bounds__(64) void softmax_kernel(
    const float* __restrict__ partial, const float* __restrict__ battn, ushort* __restrict__ attn)
{
    int hi = blockIdx.x;  // h*L + i
    int l = threadIdx.x;
    float s[6];
    #pragma unroll
    for (int u = 0; u < 6; u++) {
        size_t idx = (size_t)hi * LDIM + l + (u << 6);
        float v = battn[idx];
        #pragma unroll
        for (int c = 0; c < NCHUNK; c++) v += partial[(size_t)c * HN * LL + idx];
        s[u] = v;
    }
    float m = s[0];
    #pragma unroll
    for (int u = 1; u < 6; u++) m = fmaxf(m, s[u]);
    #pragma unroll
    for (int off = 32; off; off >>= 1) m = fmaxf(m, __shfl_xor(m, off, 64));
    float sum = 0.f;
    #pragma unroll
    for (int u = 0; u < 6; u++) { s[u] = __expf(s[u] - m); sum += s[u]; }
    #pragma unroll
    for (int off = 32; off; off >>= 1) sum += __shfl_xor(sum, off, 64);
    float inv = 1.f / sum;
    #pragma unroll
    for (int u = 0; u < 6; u++) attn[(size_t)hi * LDIM + l + (u << 6)] = f2bf(s[u] * inv);
}

// ---------------- PV via MFMA: out[n,i,c] = sum_j attn[h(c),i,j] * vt[n,c,j] ----------------
__global__ __launch_bounds__(256) void pv_mfma(const ushort* __restrict__ attn,
    const ushort* __restrict__ vt, ushort* __restrict__ outb)
{
    __shared__ ushort As[4][64][72];  // per head: [i][j]
    __shared__ ushort Bs[128][72];    // [c][j]
    int t = threadIdx.x, l = t & 63, w = t >> 6;   // wave w = head h
    int i0 = blockIdx.x << 6;
    int n  = blockIdx.y;
    int bc = t >> 1, bj = (t & 1) << 5;
    f32x4 acc[4][2] = {};
    for (int jb = 0; jb < LDIM; jb += 64) {
        const ushort* ap = attn + ((size_t)w * LDIM + i0 + l) * LDIM + jb;
        #pragma unroll
        for (int u = 0; u < 8; u++)
            *(int4*)&As[w][l][u << 3] = *(const int4*)(ap + (u << 3));
        const ushort* vp = vt + ((size_t)n * CDIM + bc) * LDIM + jb + bj;
        *(int4*)&Bs[bc][bj]      = *(const int4*)vp;
        *(int4*)&Bs[bc][bj + 8]  = *(const int4*)(vp + 8);
        *(int4*)&Bs[bc][bj + 16] = *(const int4*)(vp + 16);
        *(int4*)&Bs[bc][bj + 24] = *(const int4*)(vp + 24);
        __syncthreads();
        #pragma unroll
        for (int ks = 0; ks < 2; ks++) {
            int ko = (ks << 5) + ((l >> 4) << 3);
            bf16x8 b0 = *(const bf16x8*)&Bs[(w << 5) + (l & 15)][ko];
            bf16x8 b1 = *(const bf16x8*)&Bs[(w << 5) + 16 + (l & 15)][ko];
            #pragma unroll
            for (int mf = 0; mf < 4; mf++) {
                bf16x8 a = *(const bf16x8*)&As[w][(mf << 4) + (l & 15)][ko];
                acc[mf][0] = __builtin_amdgcn_mfma_f32_16x16x32_bf16(a, b0, acc[mf][0], 0, 0, 0);
                acc[mf][1] = __builtin_amdgcn_mfma_f32_16x16x32_bf16(a, b1, acc[mf][1], 0, 0, 0);
            }
        }
        __syncthreads();
    }
    #pragma unroll
    for (int mf = 0; mf < 4; mf++)
    #pragma unroll
    for (int nf = 0; nf < 2; nf++) {
        int c = (w << 5) + (nf << 4) + (l & 15);
        int i = i0 + (mf << 4) + ((l >> 4) << 2);
        #pragma unroll
        for (int r = 0; r < 4; r++)
            outb[((size_t)n * LDIM + i + r) * CDIM + c] = f2bf(acc[mf][nf][r]);
    }
}

extern "C" void kernel_launch(void* const* d_in, const int* in_sizes, int n_in,
                              void* d_out, int out_size, void* d_ws, size_t ws_size,
                              hipStream_t stream)
{
    const float* pair     = (const float*)d_in[0];
    const float* rbf_feat = (const float*)d_in[1];
    const float* emb_w    = (const float*)d_in[2];
    const float* emb_b    = (const float*)d_in[3];
    const float* proj_w   = (const float*)d_in[4];
    const float* proj_b   = (const float*)d_in[5];
    const float* ff_ln_w  = (const float*)d_in[30];
    const float* ff_ln_b  = (const float*)d_in[31];
    const float* ff_w1    = (const float*)d_in[32];
    const float* ff_b1    = (const float*)d_in[33];
    const float* ff_w2    = (const float*)d_in[34];
    const float* ff_b2    = (const float*)d_in[35];
    float* out = (float*)d_out;

    // workspace: 4 bf16 LLx128 regions + fp32 partial/battn + bf16 attn = 175.8 MB
    ushort* R0 = (ushort*)d_ws;              // q -> pv_out ; (R0+R1 also: rbf fp32 / FFN h1 bf16)
    ushort* R1 = R0 + (size_t)LL*CDIM;       // k -> z
    ushort* R2 = R1 + (size_t)LL*CDIM;       // v_t [n][c][j]
    ushort* R3 = R2 + (size_t)LL*CDIM;       // emb hidden -> xln (LN(P) bf16)
    float*  partialb = (float*)(R3 + (size_t)LL*CDIM);       // NCHUNK*HN*LL
    float*  battn_r  = partialb + (size_t)NCHUNK*HN*LL;      // HN*LL
    float*  battn_c  = battn_r  + (size_t)HN*LL;             // HN*LL
    ushort* attn_bf  = (ushort*)(battn_c + (size_t)HN*LL);   // HN*LL bf16

    size_t need_bytes = (size_t)4*LL*CDIM*2 + ((size_t)NCHUNK*HN*LL + 2*(size_t)HN*LL)*4
                      + (size_t)HN*LL*2;
    if (ws_size < need_bytes) return;

    const float SCALE = 0.17677669529663687f;  // 32^-0.5
    dim3 gp2(LL/64, 2), gp4(LL/64, 4);

    // rbf embedding: hidden bf16 in R3, rbf fp32 spans R0+R1
    mgemm_kernel<1,0,1><<<gp2, 256, 0, stream>>>(rbf_feat, emb_w, emb_b, nullptr, nullptr, R3,
        128, 36, 1.f, 0, 0);
    mgemm_kernel<0,1,0><<<gp2, 256, 0, stream>>>(R3, proj_w, proj_b, nullptr, nullptr, (float*)R0,
        128, 128, 1.f, 0, 0);
    battn_kernel<<<LL/4, 256, 0, stream>>>((const float*)R0, battn_r,
        (const float*)d_in[8],  (const float*)d_in[9],  (const float*)d_in[13], 1);
    battn_kernel<<<LL/4, 256, 0, stream>>>((const float*)R0, battn_c,
        (const float*)d_in[20], (const float*)d_in[21], (const float*)d_in[25], 0);

    for (int pass = 0; pass < 2; pass++) {
        const float* const* wp = (const float* const*)(d_in + (pass ? 18 : 6));
        int trans = pass ? 0 : 1;
        const float* P = pass ? (const float*)out : pair;
        const float* battnb = pass ? battn_c : battn_r;
        lnpack_kernel<<<LL/4, 256, 0, stream>>>(P, R3, wp[0], wp[1], trans);
        mgemm_kernel<0,1,1><<<gp2, 256, 0, stream>>>(R3, wp[4], nullptr, nullptr, nullptr, R0,
            128, 128, SCALE, 0, 0);
        mgemm_kernel<0,1,1><<<gp2, 256, 0, stream>>>(R3, wp[5], nullptr, nullptr, nullptr, R1,
            128, 128, 1.f/LDIM, 0, 0);
        mgemm_kernel<0,1,2><<<gp2, 256, 0, stream>>>(R3, wp[6], nullptr, nullptr, nullptr, R2,
            128, 128, 1.f, 0, 0);
        score_mfma<<<dim3(36, HN, NCHUNK), 256, 0, stream>>>(R0, R1, partialb);
        softmax_kernel<<<HN*LDIM, 64, 0, stream>>>(partialb, battnb, attn_bf);
        pv_mfma<<<dim3(LDIM/64, LDIM), 256, 0, stream>>>(attn_bf, R2, R0);
        // z = sigmoid(LN@wg+bg) * pv_out
        mgemm_kernel<2,1,1><<<gp2, 256, 0, stream>>>(R3, wp[8], wp[9], R0, nullptr, R1,
            128, 128, 1.f, 0, 0);
        // pair_out = residual + z@wo + bo
        mgemm_kernel<0,1,3><<<gp2, 256, 0, stream>>>(R1, wp[10], wp[11], nullptr, P, out,
            128, 128, 1.f, trans, trans);
    }

    // FFN: out += relu(LN(out)@w1+b1)@w2+b2  (h1 bf16 spans R0+R1)
    lnpack_kernel<<<LL/4, 256, 0, stream>>>(out, R3, ff_ln_w, ff_ln_b, 0);
    mgemm_kernel<1,1,1><<<gp4, 256, 0, stream>>>(R3, ff_w1, ff_b1, nullptr, nullptr, R0,
        256, 128, 1.f, 0, 0);
    mgemm_kernel<0,1,0><<<gp2, 256, 0, stream>>>(R0, ff_w2, ff_b2, nullptr, out, out,
        128, 256, 1.f, 0, 0);
}

// Round 5
// 1293.892 us; speedup vs baseline: 1.9592x; 1.2815x over previous
//
#include <hip/hip_runtime.h>
#include <hip/hip_bf16.h>
#include <math.h>

#define LDIM 384
#define CDIM 128
#define HN 4
#define LL (LDIM*LDIM)
#define NCHUNK 8

typedef __attribute__((ext_vector_type(8))) short bf16x8;
typedef __attribute__((ext_vector_type(4))) float f32x4;

__device__ __forceinline__ ushort f2bf(float x) {
    union { __hip_bfloat16 h; ushort u; } cv;
    cv.h = __float2bfloat16(x);
    return cv.u;
}
__device__ __forceinline__ float bf2f(ushort u) {
    union { unsigned int i; float f; } cv; cv.i = ((unsigned int)u) << 16; return cv.f;
}
// swizzled LDS byte offsets: uniform bank coverage for b128 staging + MFMA frag reads
__device__ __forceinline__ int swz256(int row, int cb) { return (row * 256 + cb) ^ ((row & 7) << 4); }
__device__ __forceinline__ int swz64 (int row, int cb) { return (row * 64  + cb) ^ ((row & 3) << 4); }

// ---------------- weight prep: fp32 [K][N] -> bf16 [N][KP] (zero-padded K) ----------------
__global__ __launch_bounds__(256) void wprep_kernel(ushort* __restrict__ wt,
    const float* emb_w, const float* proj_w,
    const float* rwq, const float* rwk, const float* rwv, const float* rwg, const float* rwo,
    const float* cwq, const float* cwk, const float* cwv, const float* cwg, const float* cwo,
    const float* ffw1, const float* ffw2)
{
    int y = blockIdx.y;
    const float* src; int N, K, KP; size_t off;
    switch (y) {
        case 0:  src = emb_w;  N = 128; K = 36;  KP = 128; off = 0;         break;
        case 1:  src = proj_w; N = 128; K = 128; KP = 128; off = 16384;     break;
        case 2:  src = rwq;    N = 128; K = 128; KP = 128; off = 2*16384;   break;
        case 3:  src = rwk;    N = 128; K = 128; KP = 128; off = 3*16384;   break;
        case 4:  src = rwv;    N = 128; K = 128; KP = 128; off = 4*16384;   break;
        case 5:  src = rwg;    N = 128; K = 128; KP = 128; off = 5*16384;   break;
        case 6:  src = rwo;    N = 128; K = 128; KP = 128; off = 6*16384;   break;
        case 7:  src = cwq;    N = 128; K = 128; KP = 128; off = 7*16384;   break;
        case 8:  src = cwk;    N = 128; K = 128; KP = 128; off = 8*16384;   break;
        case 9:  src = cwv;    N = 128; K = 128; KP = 128; off = 9*16384;   break;
        case 10: src = cwg;    N = 128; K = 128; KP = 128; off = 10*16384;  break;
        case 11: src = cwo;    N = 128; K = 128; KP = 128; off = 11*16384;  break;
        case 12: src = ffw1;   N = 256; K = 128; KP = 128; off = 12*16384;  break;
        default: src = ffw2;   N = 128; K = 256; KP = 256; off = 12*16384 + 32768; break;
    }
    int e = blockIdx.x * 256 + threadIdx.x;
    if (e >= N * KP) return;
    int nn = e / KP, kp = e - nn * KP;
    float v = (kp < K) ? src[(size_t)kp * N + nn] : 0.f;
    wt[off + e] = f2bf(v);
}

// ---------------- LN + bf16 pack ----------------
__global__ __launch_bounds__(256) void lnpack_kernel(const float* __restrict__ src,
    ushort* __restrict__ dst, const float* __restrict__ w, const float* __restrict__ b, int trans)
{
    int p = (blockIdx.x << 2) + (threadIdx.x >> 6);
    int lane = threadIdx.x & 63;
    int row = trans ? ((p % LDIM) * LDIM + p / LDIM) : p;
    float2 v = *(const float2*)(src + (size_t)row * CDIM + (lane << 1));
    float s  = v.x + v.y;
    float ss = v.x*v.x + v.y*v.y;
    #pragma unroll
    for (int off = 32; off; off >>= 1) { s += __shfl_xor(s, off, 64); ss += __shfl_xor(ss, off, 64); }
    float mean = s * (1.0f/CDIM);
    float var  = ss * (1.0f/CDIM) - mean*mean;
    float rstd = rsqrtf(var + 1e-5f);
    ushort2 o;
    o.x = f2bf((v.x - mean) * rstd * w[lane<<1]     + b[lane<<1]);
    o.y = f2bf((v.y - mean) * rstd * w[(lane<<1)+1] + b[(lane<<1)+1]);
    *(ushort2*)(dst + (size_t)p * CDIM + (lane << 1)) = o;
}

// ---------------- bias-attention ----------------
__global__ __launch_bounds__(256) void battn_kernel(const float* __restrict__ rbf,
    float* __restrict__ battn, const float* __restrict__ lnw, const float* __restrict__ lnb,
    const float* __restrict__ wb, int trans)
{
    int p = (blockIdx.x << 2) + (threadIdx.x >> 6);
    int lane = threadIdx.x & 63;
    int i = p / LDIM, j = p % LDIM;
    int srow = trans ? (j * LDIM + i) : p;
    float2 v = *(const float2*)(rbf + (size_t)srow * CDIM + (lane << 1));
    float s = v.x + v.y, ss = v.x*v.x + v.y*v.y;
    #pragma unroll
    for (int off = 32; off; off >>= 1) { s += __shfl_xor(s, off, 64); ss += __shfl_xor(ss, off, 64); }
    float mean = s*(1.f/CDIM), var = ss*(1.f/CDIM) - mean*mean, rstd = rsqrtf(var + 1e-5f);
    float x0 = (v.x - mean)*rstd*lnw[lane<<1]     + lnb[lane<<1];
    float x1 = (v.y - mean)*rstd*lnw[(lane<<1)+1] + lnb[(lane<<1)+1];
    int c0 = (lane<<1)*HN, c1 = ((lane<<1)+1)*HN;
    float a0 = x0*wb[c0+0] + x1*wb[c1+0];
    float a1 = x0*wb[c0+1] + x1*wb[c1+1];
    float a2 = x0*wb[c0+2] + x1*wb[c1+2];
    float a3 = x0*wb[c0+3] + x1*wb[c1+3];
    #pragma unroll
    for (int off = 32; off; off >>= 1) {
        a0 += __shfl_xor(a0, off, 64); a1 += __shfl_xor(a1, off, 64);
        a2 += __shfl_xor(a2, off, 64); a3 += __shfl_xor(a3, off, 64);
    }
    if (lane == 0) {
        battn[((size_t)0*LDIM + i)*LDIM + j] = a0;
        battn[((size_t)1*LDIM + i)*LDIM + j] = a1;
        battn[((size_t)2*LDIM + i)*LDIM + j] = a2;
        battn[((size_t)3*LDIM + i)*LDIM + j] = a3;
    }
}

// ------- 128x128-tile MFMA GEMM. A bf16 (or fp32 if !ABF), Wt bf16 [N][KP]. -------
// OUTMODE: 0 fp32 natural (+res), 1 bf16 natural, 3 fp32 with rtrans/otrans (+res)
template<int ACT, int ABF, int OUTMODE>
__global__ __launch_bounds__(256) void mgemm128(
    const void* __restrict__ Ain, const ushort* __restrict__ Wt,
    const float* __restrict__ bias, const float* __restrict__ res,
    void* __restrict__ Cout, int N, int KP, int lda,
    float alpha, int rtrans, int otrans)
{
    __shared__ ushort As[128*128];
    __shared__ ushort Ws[128*128];
    int t = threadIdx.x, l = t & 63, wv = t >> 6;
    int m0 = blockIdx.y << 7, n0 = blockIdx.x << 7;
    int wm = (wv >> 1) << 6, wn = (wv & 1) << 6;
    int sr = t >> 1, scb = (t & 1) << 7;
    f32x4 acc[4][4] = {};
    for (int k0 = 0; k0 < KP; k0 += 128) {
        if (k0) __syncthreads();
        if (ABF) {
            const ushort* ap = (const ushort*)Ain + (size_t)(m0 + sr) * lda + k0 + (scb >> 1);
            #pragma unroll
            for (int u = 0; u < 8; u++)
                *(int4*)((char*)As + swz256(sr, scb + (u << 4))) = *(const int4*)(ap + (u << 3));
        } else {
            const float* ap = (const float*)Ain + (size_t)(m0 + sr) * lda;
            int cb0 = scb >> 1;
            #pragma unroll
            for (int u = 0; u < 8; u++) {
                short v8[8];
                #pragma unroll
                for (int e = 0; e < 8; e++) {
                    int c = cb0 + (u << 3) + e;
                    v8[e] = (short)f2bf((c < lda) ? ap[c] : 0.f);
                }
                *(int4*)((char*)As + swz256(sr, scb + (u << 4))) = *(int4*)v8;
            }
        }
        {
            const ushort* wp2 = Wt + (size_t)(n0 + sr) * KP + k0 + (scb >> 1);
            #pragma unroll
            for (int u = 0; u < 8; u++)
                *(int4*)((char*)Ws + swz256(sr, scb + (u << 4))) = *(const int4*)(wp2 + (u << 3));
        }
        __syncthreads();
        #pragma unroll
        for (int ks = 0; ks < 4; ks++) {
            int kb = (ks << 6) + ((l >> 4) << 4);
            bf16x8 a[4], b[4];
            #pragma unroll
            for (int x = 0; x < 4; x++) {
                a[x] = *(const bf16x8*)((char*)As + swz256(wm + (x << 4) + (l & 15), kb));
                b[x] = *(const bf16x8*)((char*)Ws + swz256(wn + (x << 4) + (l & 15), kb));
            }
            #pragma unroll
            for (int i = 0; i < 4; i++)
            #pragma unroll
            for (int j = 0; j < 4; j++)
                acc[i][j] = __builtin_amdgcn_mfma_f32_16x16x32_bf16(a[i], b[j], acc[i][j], 0, 0, 0);
        }
    }
    #pragma unroll
    for (int mf = 0; mf < 4; mf++)
    #pragma unroll
    for (int nf = 0; nf < 4; nf++) {
        int col  = n0 + wn + (nf << 4) + (l & 15);
        int row0 = m0 + wm + (mf << 4) + ((l >> 4) << 2);
        float bb = bias ? bias[col] : 0.f;
        #pragma unroll
        for (int r = 0; r < 4; r++) {
            int row = row0 + r;
            float v = acc[mf][nf][r] * alpha + bb;
            if (ACT == 1) v = fmaxf(v, 0.f);
            if (ACT == 2) v = 1.f / (1.f + __expf(-v));
            if (OUTMODE == 0) {
                float o = v + (res ? res[(size_t)row * N + col] : 0.f);
                ((float*)Cout)[(size_t)row * N + col] = o;
            } else if (OUTMODE == 1) {
                ((ushort*)Cout)[(size_t)row * N + col] = f2bf(v);
            } else {
                size_t orow = otrans ? ((size_t)(row % LDIM) * LDIM + row / LDIM) : (size_t)row;
                size_t rrow = rtrans ? ((size_t)(row % LDIM) * LDIM + row / LDIM) : (size_t)row;
                float o = v + (res ? res[rrow * N + col] : 0.f);
                ((float*)Cout)[orow * N + col] = o;
            }
        }
    }
}

// ------- dual GEMM sharing A (N=128, KP=128). MODE 0: q|k bf16 natural. MODE 1: vt | sigmoid-g -------
template<int MODE>
__global__ __launch_bounds__(256) void dual_gemm(
    const ushort* __restrict__ A, const ushort* __restrict__ Wt0, const ushort* __restrict__ Wt1,
    const float* __restrict__ bias1, ushort* __restrict__ out0, ushort* __restrict__ out1,
    float alpha0, float alpha1)
{
    __shared__ ushort As[128*128];
    __shared__ ushort Ws[128*128];
    int t = threadIdx.x, l = t & 63, wv = t >> 6;
    int comp = blockIdx.x;
    int m0 = blockIdx.y << 7;
    const ushort* Wt = comp ? Wt1 : Wt0;
    int wm = (wv >> 1) << 6, wn = (wv & 1) << 6;
    int sr = t >> 1, scb = (t & 1) << 7;
    f32x4 acc[4][4] = {};
    {
        const ushort* ap = A + (size_t)(m0 + sr) * CDIM + (scb >> 1);
        const ushort* wp2 = Wt + (size_t)sr * CDIM + (scb >> 1);
        #pragma unroll
        for (int u = 0; u < 8; u++) {
            *(int4*)((char*)As + swz256(sr, scb + (u << 4))) = *(const int4*)(ap + (u << 3));
            *(int4*)((char*)Ws + swz256(sr, scb + (u << 4))) = *(const int4*)(wp2 + (u << 3));
        }
    }
    __syncthreads();
    #pragma unroll
    for (int ks = 0; ks < 4; ks++) {
        int kb = (ks << 6) + ((l >> 4) << 4);
        bf16x8 a[4], b[4];
        #pragma unroll
        for (int x = 0; x < 4; x++) {
            a[x] = *(const bf16x8*)((char*)As + swz256(wm + (x << 4) + (l & 15), kb));
            b[x] = *(const bf16x8*)((char*)Ws + swz256(wn + (x << 4) + (l & 15), kb));
        }
        #pragma unroll
        for (int i = 0; i < 4; i++)
        #pragma unroll
        for (int j = 0; j < 4; j++)
            acc[i][j] = __builtin_amdgcn_mfma_f32_16x16x32_bf16(a[i], b[j], acc[i][j], 0, 0, 0);
    }
    #pragma unroll
    for (int mf = 0; mf < 4; mf++)
    #pragma unroll
    for (int nf = 0; nf < 4; nf++) {
        int col  = wn + (nf << 4) + (l & 15);
        int row0 = m0 + wm + (mf << 4) + ((l >> 4) << 2);
        if (comp == 0) {
            if (MODE == 0) {
                #pragma unroll
                for (int r = 0; r < 4; r++)
                    out0[(size_t)(row0 + r) * CDIM + col] = f2bf(acc[mf][nf][r] * alpha0);
            } else {
                ushort4 pk;
                #pragma unroll
                for (int r = 0; r < 4; r++) ((ushort*)&pk)[r] = f2bf(acc[mf][nf][r]);
                int n = row0 / LDIM, j = row0 % LDIM;
                *(ushort4*)&out0[((size_t)n * CDIM + col) * LDIM + j] = pk;
            }
        } else {
            float bb = bias1 ? bias1[col] : 0.f;
            #pragma unroll
            for (int r = 0; r < 4; r++) {
                float v = acc[mf][nf][r] * alpha1 + bb;
                if (MODE == 1) v = 1.f / (1.f + __expf(-v));
                out1[(size_t)(row0 + r) * CDIM + col] = f2bf(v);
            }
        }
    }
}

// ------- tied scores: partial[cz,h,i,j] = sum_{n in chunk} q[n,i,h,:].k[n,j,h,:] -------
__global__ __launch_bounds__(256) void score128(const ushort* __restrict__ Q,
    const ushort* __restrict__ Kb, float* __restrict__ partial)
{
    __shared__ ushort As[128*128];
    __shared__ ushort Bs[128*128];
    int t = threadIdx.x, l = t & 63, wv = t >> 6;
    int ti = blockIdx.x / 3, tj = blockIdx.x % 3;
    int h = blockIdx.y, cz = blockIdx.z;
    int i0 = ti << 7, j0 = tj << 7;
    int wm = (wv >> 1) << 6, wn = (wv & 1) << 6;
    int sr = t >> 1, half = t & 1;
    f32x4 acc[4][4] = {};
    for (int it = 0; it < 12; it++) {
        if (it) __syncthreads();
        int nb = cz * 48 + (it << 2);
        #pragma unroll
        for (int e = 0; e < 2; e++) {
            int nq = (half << 1) + e;
            const ushort* qp = Q  + ((size_t)(nb + nq) * LDIM + i0 + sr) * CDIM + (h << 5);
            const ushort* kp = Kb + ((size_t)(nb + nq) * LDIM + j0 + sr) * CDIM + (h << 5);
            *(int4*)((char*)As + swz256(sr, (nq << 6) +  0)) = *(const int4*)qp;
            *(int4*)((char*)As + swz256(sr, (nq << 6) + 16)) = *(const int4*)(qp + 8);
            *(int4*)((char*)As + swz256(sr, (nq << 6) + 32)) = *(const int4*)(qp + 16);
            *(int4*)((char*)As + swz256(sr, (nq << 6) + 48)) = *(const int4*)(qp + 24);
            *(int4*)((char*)Bs + swz256(sr, (nq << 6) +  0)) = *(const int4*)kp;
            *(int4*)((char*)Bs + swz256(sr, (nq << 6) + 16)) = *(const int4*)(kp + 8);
            *(int4*)((char*)Bs + swz256(sr, (nq << 6) + 32)) = *(const int4*)(kp + 16);
            *(int4*)((char*)Bs + swz256(sr, (nq << 6) + 48)) = *(const int4*)(kp + 24);
        }
        __syncthreads();
        #pragma unroll
        for (int ks = 0; ks < 4; ks++) {
            int kb = (ks << 6) + ((l >> 4) << 4);
            bf16x8 a[4], b[4];
            #pragma unroll
            for (int x = 0; x < 4; x++) {
                a[x] = *(const bf16x8*)((char*)As + swz256(wm + (x << 4) + (l & 15), kb));
                b[x] = *(const bf16x8*)((char*)Bs + swz256(wn + (x << 4) + (l & 15), kb));
            }
            #pragma unroll
            for (int i = 0; i < 4; i++)
            #pragma unroll
            for (int j = 0; j < 4; j++)
                acc[i][j] = __builtin_amdgcn_mfma_f32_16x16x32_bf16(a[i], b[j], acc[i][j], 0, 0, 0);
        }
    }
    #pragma unroll
    for (int mf = 0; mf < 4; mf++)
    #pragma unroll
    for (int nf = 0; nf < 4; nf++) {
        int j = j0 + wn + (nf << 4) + (l & 15);
        int i = i0 + wm + (mf << 4) + ((l >> 4) << 2);
        #pragma unroll
        for (int r = 0; r < 4; r++)
            partial[((size_t)(cz*HN + h)*LDIM + i + r)*LDIM + j] = acc[mf][nf][r];
    }
}

// ---------------- softmax over j (chunk reduce + bias) -> bf16 ----------------
__global__ __launch_bounds__(64) void softmax_kernel(
    const float* __restrict__ partial, const float* __restrict__ battn, ushort* __restrict__ attn)
{
    int hi = blockIdx.x;
    int l = threadIdx.x;
    float s[6];
    #pragma unroll
    for (int u = 0; u < 6; u++) {
        size_t idx = (size_t)hi * LDIM + l + (u << 6);
        float v = battn[idx];
        #pragma unroll
        for (int c = 0; c < NCHUNK; c++) v += partial[(size_t)c * HN * LL + idx];
        s[u] = v;
    }
    float m = s[0];
    #pragma unroll
    for (int u = 1; u < 6; u++) m = fmaxf(m, s[u]);
    #pragma unroll
    for (int off = 32; off; off >>= 1) m = fmaxf(m, __shfl_xor(m, off, 64));
    float sum = 0.f;
    #pragma unroll
    for (int u = 0; u < 6; u++) { s[u] = __expf(s[u] - m); sum += s[u]; }
    #pragma unroll
    for (int off = 32; off; off >>= 1) sum += __shfl_xor(sum, off, 64);
    float inv = 1.f / sum;
    #pragma unroll
    for (int u = 0; u < 6; u++) attn[(size_t)hi * LDIM + l + (u << 6)] = f2bf(s[u] * inv);
}

// ------- PV with fused gate: z[n,i,c] = g[n,i,c] * sum_j attn[h(c),i,j]*vt[n,c,j] -------
__global__ __launch_bounds__(256) void pv128(const ushort* __restrict__ attn,
    const ushort* __restrict__ vt, const ushort* __restrict__ g, ushort* __restrict__ z)
{
    __shared__ ushort As[4*128*32];   // per head [i][j], swz64 within head
    __shared__ ushort Bs[128*32];     // [c][j]
    int t = threadIdx.x, l = t & 63, w = t >> 6;   // wave w = head w
    int i0 = blockIdx.x << 7;
    int n  = blockIdx.y;
    f32x4 acc[8][2] = {};
    for (int jb = 0; jb < LDIM; jb += 32) {
        if (jb) __syncthreads();
        #pragma unroll
        for (int e = 0; e < 2; e++) {
            int r = (l << 1) + e;
            const ushort* ap = attn + ((size_t)w * LDIM + i0 + r) * LDIM + jb;
            char* dst = (char*)As + (w << 13);
            *(int4*)(dst + swz64(r,  0)) = *(const int4*)ap;
            *(int4*)(dst + swz64(r, 16)) = *(const int4*)(ap + 8);
            *(int4*)(dst + swz64(r, 32)) = *(const int4*)(ap + 16);
            *(int4*)(dst + swz64(r, 48)) = *(const int4*)(ap + 24);
        }
        {
            int c = t >> 1, cb = (t & 1) << 5;
            const ushort* vp = vt + ((size_t)n * CDIM + c) * LDIM + jb + (cb >> 1);
            *(int4*)((char*)Bs + swz64(c, cb))      = *(const int4*)vp;
            *(int4*)((char*)Bs + swz64(c, cb + 16)) = *(const int4*)(vp + 8);
        }
        __syncthreads();
        int kb = (l >> 4) << 4;
        bf16x8 b0 = *(const bf16x8*)((char*)Bs + swz64((w << 5) + (l & 15), kb));
        bf16x8 b1 = *(const bf16x8*)((char*)Bs + swz64((w << 5) + 16 + (l & 15), kb));
        #pragma unroll
        for (int mf = 0; mf < 8; mf++) {
            bf16x8 a = *(const bf16x8*)((char*)As + (w << 13) + swz64((mf << 4) + (l & 15), kb));
            acc[mf][0] = __builtin_amdgcn_mfma_f32_16x16x32_bf16(a, b0, acc[mf][0], 0, 0, 0);
            acc[mf][1] = __builtin_amdgcn_mfma_f32_16x16x32_bf16(a, b1, acc[mf][1], 0, 0, 0);
        }
    }
    #pragma unroll
    for (int mf = 0; mf < 8; mf++)
    #pragma unroll
    for (int nf = 0; nf < 2; nf++) {
        int col = (w << 5) + (nf << 4) + (l & 15);
        int row0 = i0 + (mf << 4) + ((l >> 4) << 2);
        #pragma unroll
        for (int r = 0; r < 4; r++) {
            size_t p = (size_t)n * LDIM + row0 + r;
            float gv = bf2f(g[p * CDIM + col]);
            z[p * CDIM + col] = f2bf(acc[mf][nf][r] * gv);
        }
    }
}

extern "C" void kernel_launch(void* const* d_in, const int* in_sizes, int n_in,
                              void* d_out, int out_size, void* d_ws, size_t ws_size,
                              hipStream_t stream)
{
    const float* pair     = (const float*)d_in[0];
    const float* rbf_feat = (const float*)d_in[1];
    const float* emb_b    = (const float*)d_in[3];
    const float* proj_b   = (const float*)d_in[5];
    const float* ff_ln_w  = (const float*)d_in[30];
    const float* ff_ln_b  = (const float*)d_in[31];
    const float* ff_b1    = (const float*)d_in[33];
    const float* ff_b2    = (const float*)d_in[35];
    float* out = (float*)d_out;

    // workspace: 4 bf16 LLx128 regions + partial + battn x2 + attn + Wt arena = 176.3 MB
    ushort* R0 = (ushort*)d_ws;
    ushort* R1 = R0 + (size_t)LL*CDIM;
    ushort* R2 = R1 + (size_t)LL*CDIM;
    ushort* R3 = R2 + (size_t)LL*CDIM;
    float*  partialb = (float*)(R3 + (size_t)LL*CDIM);
    float*  battn_r  = partialb + (size_t)NCHUNK*HN*LL;
    float*  battn_c  = battn_r  + (size_t)HN*LL;
    ushort* attn_bf  = (ushort*)(battn_c + (size_t)HN*LL);
    ushort* wt       = attn_bf + (size_t)HN*LL;

    size_t need_bytes = (size_t)4*LL*CDIM*2 + ((size_t)NCHUNK*HN*LL + 2*(size_t)HN*LL)*4
                      + (size_t)HN*LL*2 + (size_t)262144*2;
    if (ws_size < need_bytes) return;

    const size_t WS = 16384;
    ushort* wt_emb  = wt;
    ushort* wt_proj = wt + WS;
    ushort* wt_ff1  = wt + 12*WS;
    ushort* wt_ff2  = wt + 12*WS + 32768;

    const float SCALE = 0.17677669529663687f;  // 32^-0.5

    wprep_kernel<<<dim3(128, 14), 256, 0, stream>>>(wt,
        (const float*)d_in[2], (const float*)d_in[4],
        (const float*)d_in[10], (const float*)d_in[11], (const float*)d_in[12],
        (const float*)d_in[14], (const float*)d_in[16],
        (const float*)d_in[22], (const float*)d_in[23], (const float*)d_in[24],
        (const float*)d_in[26], (const float*)d_in[28],
        (const float*)d_in[32], (const float*)d_in[34]);

    // rbf = relu(rbf_feat@emb+eb)@proj+pb : hidden bf16 -> R3; rbf fp32 spans R0+R1
    mgemm128<1,0,1><<<dim3(1,1152), 256, 0, stream>>>(rbf_feat, wt_emb, emb_b, nullptr, R3,
        128, 128, 36, 1.f, 0, 0);
    mgemm128<0,1,0><<<dim3(1,1152), 256, 0, stream>>>(R3, wt_proj, proj_b, nullptr, (float*)R0,
        128, 128, 128, 1.f, 0, 0);
    battn_kernel<<<LL/4, 256, 0, stream>>>((const float*)R0, battn_r,
        (const float*)d_in[8],  (const float*)d_in[9],  (const float*)d_in[13], 1);
    battn_kernel<<<LL/4, 256, 0, stream>>>((const float*)R0, battn_c,
        (const float*)d_in[20], (const float*)d_in[21], (const float*)d_in[25], 0);

    for (int pass = 0; pass < 2; pass++) {
        const float* const* wp = (const float* const*)(d_in + (pass ? 18 : 6));
        int trans = pass ? 0 : 1;
        const float* P = pass ? (const float*)out : pair;
        const float* battnb = pass ? battn_c : battn_r;
        int ws0 = pass ? 7 : 2;   // wq slot; k,v,g,o follow
        lnpack_kernel<<<LL/4, 256, 0, stream>>>(P, R3, wp[0], wp[1], trans);
        dual_gemm<0><<<dim3(2,1152), 256, 0, stream>>>(R3, wt + ws0*WS, wt + (ws0+1)*WS,
            nullptr, R0, R1, SCALE, 1.f/LDIM);
        score128<<<dim3(9, HN, NCHUNK), 256, 0, stream>>>(R0, R1, partialb);
        softmax_kernel<<<HN*LDIM, 64, 0, stream>>>(partialb, battnb, attn_bf);
        dual_gemm<1><<<dim3(2,1152), 256, 0, stream>>>(R3, wt + (ws0+2)*WS, wt + (ws0+3)*WS,
            wp[9], R0, R1, 1.f, 1.f);
        pv128<<<dim3(3, LDIM), 256, 0, stream>>>(attn_bf, R0, R1, R2);
        mgemm128<0,1,3><<<dim3(1,1152), 256, 0, stream>>>(R2, wt + (ws0+4)*WS, wp[11], P, out,
            128, 128, 128, 1.f, trans, trans);
    }

    // FFN: out += relu(LN(out)@w1+b1)@w2+b2  (h1 bf16 [LL][256] spans R0+R1)
    lnpack_kernel<<<LL/4, 256, 0, stream>>>(out, R3, ff_ln_w, ff_ln_b, 0);
    mgemm128<1,1,1><<<dim3(2,1152), 256, 0, stream>>>(R3, wt_ff1, ff_b1, nullptr, R0,
        256, 128, 128, 1.f, 0, 0);
    mgemm128<0,1,0><<<dim3(1,1152), 256, 0, stream>>>(R0, wt_ff2, ff_b2, out, out,
        128, 256, 256, 1.f, 0, 0);
}

// Round 6
// 1026.155 us; speedup vs baseline: 2.4704x; 1.2609x over previous
//
#include <hip/hip_runtime.h>
#include <hip/hip_bf16.h>
#include <math.h>

#define LDIM 384
#define CDIM 128
#define HN 4
#define LL (LDIM*LDIM)
#define NCHUNK 8
#define VTPLANE ((size_t)12288*384)

typedef __attribute__((ext_vector_type(8))) short bf16x8;
typedef __attribute__((ext_vector_type(4))) float f32x4;

__device__ __forceinline__ ushort f2bf(float x) {
    union { __hip_bfloat16 h; ushort u; } cv;
    cv.h = __float2bfloat16(x);
    return cv.u;
}
__device__ __forceinline__ float bf2f(ushort u) {
    union { unsigned int i; float f; } cv; cv.i = ((unsigned int)u) << 16; return cv.f;
}
// swizzle: row stride 256B, XOR spreads 8 x 16B spans -> full 32-bank coverage
__device__ __forceinline__ int swz256(int row, int cb) { return (row * 256 + cb) ^ ((row & 7) << 4); }

// ---------------- weight prep: fp32 [K][N] -> bf16 [N][KP] (zero-padded K) ----------------
__global__ __launch_bounds__(256) void wprep_kernel(ushort* __restrict__ wt,
    const float* emb_w, const float* proj_w,
    const float* rwq, const float* rwk, const float* rwv, const float* rwg, const float* rwo,
    const float* cwq, const float* cwk, const float* cwv, const float* cwg, const float* cwo,
    const float* ffw1, const float* ffw2)
{
    int y = blockIdx.y;
    const float* src; int N, K, KP; size_t off;
    switch (y) {
        case 0:  src = emb_w;  N = 128; K = 36;  KP = 128; off = 0;         break;
        case 1:  src = proj_w; N = 128; K = 128; KP = 128; off = 16384;     break;
        case 2:  src = rwq;    N = 128; K = 128; KP = 128; off = 2*16384;   break;
        case 3:  src = rwk;    N = 128; K = 128; KP = 128; off = 3*16384;   break;
        case 4:  src = rwv;    N = 128; K = 128; KP = 128; off = 4*16384;   break;
        case 5:  src = rwg;    N = 128; K = 128; KP = 128; off = 5*16384;   break;
        case 6:  src = rwo;    N = 128; K = 128; KP = 128; off = 6*16384;   break;
        case 7:  src = cwq;    N = 128; K = 128; KP = 128; off = 7*16384;   break;
        case 8:  src = cwk;    N = 128; K = 128; KP = 128; off = 8*16384;   break;
        case 9:  src = cwv;    N = 128; K = 128; KP = 128; off = 9*16384;   break;
        case 10: src = cwg;    N = 128; K = 128; KP = 128; off = 10*16384;  break;
        case 11: src = cwo;    N = 128; K = 128; KP = 128; off = 11*16384;  break;
        case 12: src = ffw1;   N = 256; K = 128; KP = 128; off = 12*16384;  break;
        default: src = ffw2;   N = 128; K = 256; KP = 256; off = 12*16384 + 32768; break;
    }
    int e = blockIdx.x * 256 + threadIdx.x;
    if (e >= N * KP) return;
    int nn = e / KP, kp = e - nn * KP;
    float v = (kp < K) ? src[(size_t)kp * N + nn] : 0.f;
    wt[off + e] = f2bf(v);
}

// ------- LN + bf16 pack: coalesced read of src row p, write to dst row trans(p) -------
__global__ __launch_bounds__(256) void lnpack_kernel(const float* __restrict__ src,
    ushort* __restrict__ dst, const float* __restrict__ w, const float* __restrict__ b, int trans)
{
    int p = (blockIdx.x << 2) + (threadIdx.x >> 6);
    int lane = threadIdx.x & 63;
    float2 v = *(const float2*)(src + (size_t)p * CDIM + (lane << 1));
    float s  = v.x + v.y;
    float ss = v.x*v.x + v.y*v.y;
    #pragma unroll
    for (int off = 32; off; off >>= 1) { s += __shfl_xor(s, off, 64); ss += __shfl_xor(ss, off, 64); }
    float mean = s * (1.0f/CDIM);
    float var  = ss * (1.0f/CDIM) - mean*mean;
    float rstd = rsqrtf(var + 1e-5f);
    int q = trans ? ((p % LDIM) * LDIM + p / LDIM) : p;
    ushort2 o;
    o.x = f2bf((v.x - mean) * rstd * w[lane<<1]     + b[lane<<1]);
    o.y = f2bf((v.y - mean) * rstd * w[(lane<<1)+1] + b[(lane<<1)+1]);
    *(ushort2*)(dst + (size_t)q * CDIM + (lane << 1)) = o;
}

// ------- bias-attention: coalesced read rbf row p=(a,b); write battn[h, i, j] (trans swaps) -------
__global__ __launch_bounds__(256) void battn_kernel(const float* __restrict__ rbf,
    float* __restrict__ battn, const float* __restrict__ lnw, const float* __restrict__ lnb,
    const float* __restrict__ wb, int trans)
{
    int p = (blockIdx.x << 2) + (threadIdx.x >> 6);
    int lane = threadIdx.x & 63;
    int a = p / LDIM, b2 = p % LDIM;
    float2 v = *(const float2*)(rbf + (size_t)p * CDIM + (lane << 1));
    float s = v.x + v.y, ss = v.x*v.x + v.y*v.y;
    #pragma unroll
    for (int off = 32; off; off >>= 1) { s += __shfl_xor(s, off, 64); ss += __shfl_xor(ss, off, 64); }
    float mean = s*(1.f/CDIM), var = ss*(1.f/CDIM) - mean*mean, rstd = rsqrtf(var + 1e-5f);
    float x0 = (v.x - mean)*rstd*lnw[lane<<1]     + lnb[lane<<1];
    float x1 = (v.y - mean)*rstd*lnw[(lane<<1)+1] + lnb[(lane<<1)+1];
    int c0 = (lane<<1)*HN, c1 = ((lane<<1)+1)*HN;
    float a0 = x0*wb[c0+0] + x1*wb[c1+0];
    float a1 = x0*wb[c0+1] + x1*wb[c1+1];
    float a2 = x0*wb[c0+2] + x1*wb[c1+2];
    float a3 = x0*wb[c0+3] + x1*wb[c1+3];
    #pragma unroll
    for (int off = 32; off; off >>= 1) {
        a0 += __shfl_xor(a0, off, 64); a1 += __shfl_xor(a1, off, 64);
        a2 += __shfl_xor(a2, off, 64); a3 += __shfl_xor(a3, off, 64);
    }
    if (lane == 0) {
        int io = trans ? b2 : a, jo = trans ? a : b2;
        battn[((size_t)0*LDIM + io)*LDIM + jo] = a0;
        battn[((size_t)1*LDIM + io)*LDIM + jo] = a1;
        battn[((size_t)2*LDIM + io)*LDIM + jo] = a2;
        battn[((size_t)3*LDIM + io)*LDIM + jo] = a3;
    }
}

// ------- 128x128-tile MFMA GEMM. AMODE: 0 fp32, 1 bf16, 2 bf16 gated (A*gmul elementwise). -------
// OUTMODE: 0 fp32 natural (+res), 1 bf16 natural, 3 fp32 with rtrans/otrans (+res)
template<int ACT, int AMODE, int OUTMODE>
__global__ __launch_bounds__(256) void mgemm128(
    const void* __restrict__ Ain, const ushort* __restrict__ Wt,
    const float* __restrict__ bias, const ushort* __restrict__ gmul,
    const float* __restrict__ res, void* __restrict__ Cout,
    int N, int KP, int lda, float alpha, int rtrans, int otrans)
{
    __shared__ ushort As[128*128];
    __shared__ ushort Ws[128*128];
    int t = threadIdx.x, l = t & 63, wv = t >> 6;
    int m0 = blockIdx.y << 7, n0 = blockIdx.x << 7;
    int wm = (wv >> 1) << 6, wn = (wv & 1) << 6;
    int sr = t >> 1, scb = (t & 1) << 7;
    f32x4 acc[4][4] = {};
    for (int k0 = 0; k0 < KP; k0 += 128) {
        if (k0) __syncthreads();
        if (AMODE == 1) {
            const ushort* ap = (const ushort*)Ain + (size_t)(m0 + sr) * lda + k0 + (scb >> 1);
            #pragma unroll
            for (int u = 0; u < 8; u++)
                *(int4*)((char*)As + swz256(sr, scb + (u << 4))) = *(const int4*)(ap + (u << 3));
        } else if (AMODE == 2) {
            const ushort* ap = (const ushort*)Ain + (size_t)(m0 + sr) * lda + k0 + (scb >> 1);
            const ushort* gp = gmul + (size_t)(m0 + sr) * lda + k0 + (scb >> 1);
            #pragma unroll
            for (int u = 0; u < 8; u++) {
                int4 av = *(const int4*)(ap + (u << 3));
                int4 gv = *(const int4*)(gp + (u << 3));
                ushort* au = (ushort*)&av; ushort* gu = (ushort*)&gv;
                short v8[8];
                #pragma unroll
                for (int e = 0; e < 8; e++) v8[e] = (short)f2bf(bf2f(au[e]) * bf2f(gu[e]));
                *(int4*)((char*)As + swz256(sr, scb + (u << 4))) = *(int4*)v8;
            }
        } else {
            const float* ap = (const float*)Ain + (size_t)(m0 + sr) * lda;
            int cb0 = scb >> 1;
            #pragma unroll
            for (int u = 0; u < 8; u++) {
                short v8[8];
                #pragma unroll
                for (int e = 0; e < 8; e++) {
                    int c = cb0 + (u << 3) + e;
                    v8[e] = (short)f2bf((c < lda) ? ap[c] : 0.f);
                }
                *(int4*)((char*)As + swz256(sr, scb + (u << 4))) = *(int4*)v8;
            }
        }
        {
            const ushort* wp2 = Wt + (size_t)(n0 + sr) * KP + k0 + (scb >> 1);
            #pragma unroll
            for (int u = 0; u < 8; u++)
                *(int4*)((char*)Ws + swz256(sr, scb + (u << 4))) = *(const int4*)(wp2 + (u << 3));
        }
        __syncthreads();
        #pragma unroll
        for (int ks = 0; ks < 4; ks++) {
            int kb = (ks << 6) + ((l >> 4) << 4);
            bf16x8 a[4], b[4];
            #pragma unroll
            for (int x = 0; x < 4; x++) {
                a[x] = *(const bf16x8*)((char*)As + swz256(wm + (x << 4) + (l & 15), kb));
                b[x] = *(const bf16x8*)((char*)Ws + swz256(wn + (x << 4) + (l & 15), kb));
            }
            #pragma unroll
            for (int i = 0; i < 4; i++)
            #pragma unroll
            for (int j = 0; j < 4; j++)
                acc[i][j] = __builtin_amdgcn_mfma_f32_16x16x32_bf16(a[i], b[j], acc[i][j], 0, 0, 0);
        }
    }
    #pragma unroll
    for (int mf = 0; mf < 4; mf++)
    #pragma unroll
    for (int nf = 0; nf < 4; nf++) {
        int col  = n0 + wn + (nf << 4) + (l & 15);
        int row0 = m0 + wm + (mf << 4) + ((l >> 4) << 2);
        float bb = bias ? bias[col] : 0.f;
        #pragma unroll
        for (int r = 0; r < 4; r++) {
            int row = row0 + r;
            float v = acc[mf][nf][r] * alpha + bb;
            if (ACT == 1) v = fmaxf(v, 0.f);
            if (ACT == 2) v = 1.f / (1.f + __expf(-v));
            if (OUTMODE == 0) {
                float o = v + (res ? res[(size_t)row * N + col] : 0.f);
                ((float*)Cout)[(size_t)row * N + col] = o;
            } else if (OUTMODE == 1) {
                ((ushort*)Cout)[(size_t)row * N + col] = f2bf(v);
            } else {
                size_t orow = otrans ? ((size_t)(row % LDIM) * LDIM + row / LDIM) : (size_t)row;
                size_t rrow = rtrans ? ((size_t)(row % LDIM) * LDIM + row / LDIM) : (size_t)row;
                float o = v + (res ? res[rrow * N + col] : 0.f);
                ((float*)Cout)[orow * N + col] = o;
            }
        }
    }
}

// ------- q,k,v in one kernel: A-tile staged ONCE, loop 3 weight tiles. -------
// q -> natural bf16 *SCALE ; k -> natural *1/L ; v -> vt[h][(n*32+d)][j]
__global__ __launch_bounds__(256) void qkv3_gemm(
    const ushort* __restrict__ A, const ushort* __restrict__ wt3,
    ushort* __restrict__ qo, ushort* __restrict__ ko, ushort* __restrict__ vt,
    float scale_q, float scale_k)
{
    __shared__ ushort As[128*128];
    __shared__ ushort Ws[128*128];
    int t = threadIdx.x, l = t & 63, wv = t >> 6;
    int m0 = blockIdx.x << 7;
    int wm = (wv >> 1) << 6, wn = (wv & 1) << 6;
    int sr = t >> 1, scb = (t & 1) << 7;
    {
        const ushort* ap = A + (size_t)(m0 + sr) * CDIM + (scb >> 1);
        #pragma unroll
        for (int u = 0; u < 8; u++)
            *(int4*)((char*)As + swz256(sr, scb + (u << 4))) = *(const int4*)(ap + (u << 3));
    }
    for (int comp = 0; comp < 3; comp++) {
        if (comp) __syncthreads();
        const ushort* wp2 = wt3 + (size_t)comp * 16384 + (size_t)sr * CDIM + (scb >> 1);
        #pragma unroll
        for (int u = 0; u < 8; u++)
            *(int4*)((char*)Ws + swz256(sr, scb + (u << 4))) = *(const int4*)(wp2 + (u << 3));
        __syncthreads();
        f32x4 acc[4][4] = {};
        #pragma unroll
        for (int ks = 0; ks < 4; ks++) {
            int kb = (ks << 6) + ((l >> 4) << 4);
            bf16x8 a[4], b[4];
            #pragma unroll
            for (int x = 0; x < 4; x++) {
                a[x] = *(const bf16x8*)((char*)As + swz256(wm + (x << 4) + (l & 15), kb));
                b[x] = *(const bf16x8*)((char*)Ws + swz256(wn + (x << 4) + (l & 15), kb));
            }
            #pragma unroll
            for (int i = 0; i < 4; i++)
            #pragma unroll
            for (int j = 0; j < 4; j++)
                acc[i][j] = __builtin_amdgcn_mfma_f32_16x16x32_bf16(a[i], b[j], acc[i][j], 0, 0, 0);
        }
        #pragma unroll
        for (int mf = 0; mf < 4; mf++)
        #pragma unroll
        for (int nf = 0; nf < 4; nf++) {
            int col  = wn + (nf << 4) + (l & 15);
            int row0 = m0 + wm + (mf << 4) + ((l >> 4) << 2);
            if (comp == 0) {
                #pragma unroll
                for (int r = 0; r < 4; r++)
                    qo[(size_t)(row0 + r) * CDIM + col] = f2bf(acc[mf][nf][r] * scale_q);
            } else if (comp == 1) {
                #pragma unroll
                for (int r = 0; r < 4; r++)
                    ko[(size_t)(row0 + r) * CDIM + col] = f2bf(acc[mf][nf][r] * scale_k);
            } else {
                ushort4 pk;
                #pragma unroll
                for (int r = 0; r < 4; r++) ((ushort*)&pk)[r] = f2bf(acc[mf][nf][r]);
                int n = row0 / LDIM, j = row0 % LDIM;   // 4-row groups never cross n
                size_t vrow = (size_t)(col >> 5) * VTPLANE / 384 * 0  // (silence)
                            ;
                (void)vrow;
                *(ushort4*)&vt[((size_t)(col >> 5) * 12288 + (size_t)n * 32 + (col & 31)) * 384 + j] = pk;
            }
        }
    }
}

// ------- tied scores: partial[cz,h,i,j] = sum_{n in chunk} q[n,i,h,:].k[n,j,h,:] -------
__global__ __launch_bounds__(256) void score128(const ushort* __restrict__ Q,
    const ushort* __restrict__ Kb, float* __restrict__ partial)
{
    __shared__ ushort As[128*128];
    __shared__ ushort Bs[128*128];
    int t = threadIdx.x, l = t & 63, wv = t >> 6;
    int ti = blockIdx.x / 3, tj = blockIdx.x % 3;
    int h = blockIdx.y, cz = blockIdx.z;
    int i0 = ti << 7, j0 = tj << 7;
    int wm = (wv >> 1) << 6, wn = (wv & 1) << 6;
    int sr = t >> 1, half = t & 1;
    f32x4 acc[4][4] = {};
    for (int it = 0; it < 12; it++) {
        if (it) __syncthreads();
        int nb = cz * 48 + (it << 2);
        #pragma unroll
        for (int e = 0; e < 2; e++) {
            int nq = (half << 1) + e;
            const ushort* qp = Q  + ((size_t)(nb + nq) * LDIM + i0 + sr) * CDIM + (h << 5);
            const ushort* kp = Kb + ((size_t)(nb + nq) * LDIM + j0 + sr) * CDIM + (h << 5);
            *(int4*)((char*)As + swz256(sr, (nq << 6) +  0)) = *(const int4*)qp;
            *(int4*)((char*)As + swz256(sr, (nq << 6) + 16)) = *(const int4*)(qp + 8);
            *(int4*)((char*)As + swz256(sr, (nq << 6) + 32)) = *(const int4*)(qp + 16);
            *(int4*)((char*)As + swz256(sr, (nq << 6) + 48)) = *(const int4*)(qp + 24);
            *(int4*)((char*)Bs + swz256(sr, (nq << 6) +  0)) = *(const int4*)kp;
            *(int4*)((char*)Bs + swz256(sr, (nq << 6) + 16)) = *(const int4*)(kp + 8);
            *(int4*)((char*)Bs + swz256(sr, (nq << 6) + 32)) = *(const int4*)(kp + 16);
            *(int4*)((char*)Bs + swz256(sr, (nq << 6) + 48)) = *(const int4*)(kp + 24);
        }
        __syncthreads();
        #pragma unroll
        for (int ks = 0; ks < 4; ks++) {
            int kb = (ks << 6) + ((l >> 4) << 4);
            bf16x8 a[4], b[4];
            #pragma unroll
            for (int x = 0; x < 4; x++) {
                a[x] = *(const bf16x8*)((char*)As + swz256(wm + (x << 4) + (l & 15), kb));
                b[x] = *(const bf16x8*)((char*)Bs + swz256(wn + (x << 4) + (l & 15), kb));
            }
            #pragma unroll
            for (int i = 0; i < 4; i++)
            #pragma unroll
            for (int j = 0; j < 4; j++)
                acc[i][j] = __builtin_amdgcn_mfma_f32_16x16x32_bf16(a[i], b[j], acc[i][j], 0, 0, 0);
        }
    }
    #pragma unroll
    for (int mf = 0; mf < 4; mf++)
    #pragma unroll
    for (int nf = 0; nf < 4; nf++) {
        int j = j0 + wn + (nf << 4) + (l & 15);
        int i = i0 + wm + (mf << 4) + ((l >> 4) << 2);
        #pragma unroll
        for (int r = 0; r < 4; r++)
            partial[((size_t)(cz*HN + h)*LDIM + i + r)*LDIM + j] = acc[mf][nf][r];
    }
}

// ---------------- softmax over j (chunk reduce + bias) -> bf16 ----------------
__global__ __launch_bounds__(64) void softmax_kernel(
    const float* __restrict__ partial, const float* __restrict__ battn, ushort* __restrict__ attn)
{
    int hi = blockIdx.x;
    int l = threadIdx.x;
    float s[6];
    #pragma unroll
    for (int u = 0; u < 6; u++) {
        size_t idx = (size_t)hi * LDIM + l + (u << 6);
        float v = battn[idx];
        #pragma unroll
        for (int c = 0; c < NCHUNK; c++) v += partial[(size_t)c * HN * LL + idx];
        s[u] = v;
    }
    float m = s[0];
    #pragma unroll
    for (int u = 1; u < 6; u++) m = fmaxf(m, s[u]);
    #pragma unroll
    for (int off = 32; off; off >>= 1) m = fmaxf(m, __shfl_xor(m, off, 64));
    float sum = 0.f;
    #pragma unroll
    for (int u = 0; u < 6; u++) { s[u] = __expf(s[u] - m); sum += s[u]; }
    #pragma unroll
    for (int off = 32; off; off >>= 1) sum += __shfl_xor(sum, off, 64);
    float inv = 1.f / sum;
    #pragma unroll
    for (int u = 0; u < 6; u++) attn[(size_t)hi * LDIM + l + (u << 6)] = f2bf(s[u] * inv);
}

// ------- PV as per-head GEMM: pvout[(n,i),h*32+d] = sum_j attn[h,i,j]*vt[h][(n,d)][j] -------
// grid (96 col-tiles, 3 i-tiles, 4 heads)
__global__ __launch_bounds__(256) void pvg_gemm(const ushort* __restrict__ attn,
    const ushort* __restrict__ vt, ushort* __restrict__ pvout)
{
    __shared__ ushort As[128*128];
    __shared__ ushort Ws[128*128];
    int t = threadIdx.x, l = t & 63, wv = t >> 6;
    int n0 = blockIdx.x << 7;   // col in [0,12288)
    int i0 = blockIdx.y << 7;   // row in [0,384)
    int h  = blockIdx.z;
    const ushort* abase = attn + (size_t)h * LL;
    const ushort* bbase = vt + (size_t)h * VTPLANE;
    int wm = (wv >> 1) << 6, wn = (wv & 1) << 6;
    int sr = t >> 1, scb = (t & 1) << 7;
    f32x4 acc[4][4] = {};
    for (int k0 = 0; k0 < LDIM; k0 += 128) {
        if (k0) __syncthreads();
        {
            const ushort* ap = abase + (size_t)(i0 + sr) * LDIM + k0 + (scb >> 1);
            const ushort* bp = bbase + (size_t)(n0 + sr) * LDIM + k0 + (scb >> 1);
            #pragma unroll
            for (int u = 0; u < 8; u++) {
                *(int4*)((char*)As + swz256(sr, scb + (u << 4))) = *(const int4*)(ap + (u << 3));
                *(int4*)((char*)Ws + swz256(sr, scb + (u << 4))) = *(const int4*)(bp + (u << 3));
            }
        }
        __syncthreads();
        #pragma unroll
        for (int ks = 0; ks < 4; ks++) {
            int kb = (ks << 6) + ((l >> 4) << 4);
            bf16x8 a[4], b[4];
            #pragma unroll
            for (int x = 0; x < 4; x++) {
                a[x] = *(const bf16x8*)((char*)As + swz256(wm + (x << 4) + (l & 15), kb));
                b[x] = *(const bf16x8*)((char*)Ws + swz256(wn + (x << 4) + (l & 15), kb));
            }
            #pragma unroll
            for (int i = 0; i < 4; i++)
            #pragma unroll
            for (int j = 0; j < 4; j++)
                acc[i][j] = __builtin_amdgcn_mfma_f32_16x16x32_bf16(a[i], b[j], acc[i][j], 0, 0, 0);
        }
    }
    #pragma unroll
    for (int mf = 0; mf < 4; mf++)
    #pragma unroll
    for (int nf = 0; nf < 4; nf++) {
        int col  = n0 + wn + (nf << 4) + (l & 15);   // n*32+d
        int row0 = i0 + wm + (mf << 4) + ((l >> 4) << 2);
        int n = col >> 5, d = col & 31;
        #pragma unroll
        for (int r = 0; r < 4; r++) {
            int i = row0 + r;
            pvout[((size_t)n * LDIM + i) * CDIM + (h << 5) + d] = f2bf(acc[mf][nf][r]);
        }
    }
}

extern "C" void kernel_launch(void* const* d_in, const int* in_sizes, int n_in,
                              void* d_out, int out_size, void* d_ws, size_t ws_size,
                              hipStream_t stream)
{
    const float* pair     = (const float*)d_in[0];
    const float* rbf_feat = (const float*)d_in[1];
    const float* emb_b    = (const float*)d_in[3];
    const float* proj_b   = (const float*)d_in[5];
    const float* ff_ln_w  = (const float*)d_in[30];
    const float* ff_ln_b  = (const float*)d_in[31];
    const float* ff_b1    = (const float*)d_in[33];
    const float* ff_b2    = (const float*)d_in[35];
    float* out = (float*)d_out;

    // workspace: 4 bf16 LLx128 regions + partial + battn x2 + attn + Wt arena = 176.3 MB
    ushort* R0 = (ushort*)d_ws;              // q -> pvout
    ushort* R1 = R0 + (size_t)LL*CDIM;       // k -> g
    ushort* R2 = R1 + (size_t)LL*CDIM;       // vt [h][(n,d)][j]
    ushort* R3 = R2 + (size_t)LL*CDIM;       // xln (LN(P) bf16)
    float*  partialb = (float*)(R3 + (size_t)LL*CDIM);
    float*  battn_r  = partialb + (size_t)NCHUNK*HN*LL;
    float*  battn_c  = battn_r  + (size_t)HN*LL;
    ushort* attn_bf  = (ushort*)(battn_c + (size_t)HN*LL);
    ushort* wt       = attn_bf + (size_t)HN*LL;

    size_t need_bytes = (size_t)4*LL*CDIM*2 + ((size_t)NCHUNK*HN*LL + 2*(size_t)HN*LL)*4
                      + (size_t)HN*LL*2 + (size_t)262144*2;
    if (ws_size < need_bytes) return;

    const size_t WS = 16384;
    ushort* wt_emb  = wt;
    ushort* wt_proj = wt + WS;
    ushort* wt_ff1  = wt + 12*WS;
    ushort* wt_ff2  = wt + 12*WS + 32768;

    const float SCALE = 0.17677669529663687f;  // 32^-0.5

    wprep_kernel<<<dim3(128, 14), 256, 0, stream>>>(wt,
        (const float*)d_in[2], (const float*)d_in[4],
        (const float*)d_in[10], (const float*)d_in[11], (const float*)d_in[12],
        (const float*)d_in[14], (const float*)d_in[16],
        (const float*)d_in[22], (const float*)d_in[23], (const float*)d_in[24],
        (const float*)d_in[26], (const float*)d_in[28],
        (const float*)d_in[32], (const float*)d_in[34]);

    // rbf = relu(rbf_feat@emb+eb)@proj+pb : hidden bf16 -> R3; rbf fp32 spans R0+R1
    mgemm128<1,0,1><<<dim3(1,1152), 256, 0, stream>>>(rbf_feat, wt_emb, emb_b, nullptr, nullptr, R3,
        128, 128, 36, 1.f, 0, 0);
    mgemm128<0,1,0><<<dim3(1,1152), 256, 0, stream>>>(R3, wt_proj, proj_b, nullptr, nullptr, (float*)R0,
        128, 128, 128, 1.f, 0, 0);
    battn_kernel<<<LL/4, 256, 0, stream>>>((const float*)R0, battn_r,
        (const float*)d_in[8],  (const float*)d_in[9],  (const float*)d_in[13], 1);
    battn_kernel<<<LL/4, 256, 0, stream>>>((const float*)R0, battn_c,
        (const float*)d_in[20], (const float*)d_in[21], (const float*)d_in[25], 0);

    for (int pass = 0; pass < 2; pass++) {
        const float* const* wp = (const float* const*)(d_in + (pass ? 18 : 6));
        int trans = pass ? 0 : 1;
        const float* P = pass ? (const float*)out : pair;
        const float* battnb = pass ? battn_c : battn_r;
        int ws0 = pass ? 7 : 2;   // wq slot; k,v,g,o follow
        lnpack_kernel<<<LL/4, 256, 0, stream>>>(P, R3, wp[0], wp[1], trans);
        qkv3_gemm<<<1152, 256, 0, stream>>>(R3, wt + ws0*WS, R0, R1, R2, SCALE, 1.f/LDIM);
        score128<<<dim3(9, HN, NCHUNK), 256, 0, stream>>>(R0, R1, partialb);
        softmax_kernel<<<HN*LDIM, 64, 0, stream>>>(partialb, battnb, attn_bf);
        // g = sigmoid(xln@wg+bg) -> R1 (k dead after score)
        mgemm128<2,1,1><<<dim3(1,1152), 256, 0, stream>>>(R3, wt + (ws0+3)*WS, wp[9], nullptr, nullptr, R1,
            128, 128, 128, 1.f, 0, 0);
        // pvout -> R0 (q dead)
        pvg_gemm<<<dim3(96, 3, 4), 256, 0, stream>>>(attn_bf, R2, R0);
        // pair_out = residual + (g .* pv)@wo + bo   (gate fused into A-staging)
        mgemm128<0,2,3><<<dim3(1,1152), 256, 0, stream>>>(R0, wt + (ws0+4)*WS, wp[11], R1, P, out,
            128, 128, 128, 1.f, trans, trans);
    }

    // FFN: out += relu(LN(out)@w1+b1)@w2+b2  (h1 bf16 [LL][256] spans R0+R1)
    lnpack_kernel<<<LL/4, 256, 0, stream>>>(out, R3, ff_ln_w, ff_ln_b, 0);
    mgemm128<1,1,1><<<dim3(2,1152), 256, 0, stream>>>(R3, wt_ff1, ff_b1, nullptr, nullptr, R0,
        256, 128, 128, 1.f, 0, 0);
    mgemm128<0,1,0><<<dim3(1,1152), 256, 0, stream>>>(R0, wt_ff2, ff_b2, nullptr, out, out,
        128, 256, 256, 1.f, 0, 0);
}

// Round 7
// 818.371 us; speedup vs baseline: 3.0976x; 1.2539x over previous
//
#include <hip/hip_runtime.h>
#include <hip/hip_bf16.h>
#include <math.h>

#define LDIM 384
#define CDIM 128
#define HN 4
#define LL (LDIM*LDIM)
#define NCHUNK 8
#define VTPLANE ((size_t)12288*384)

typedef __attribute__((ext_vector_type(8))) short bf16x8;
typedef __attribute__((ext_vector_type(4))) float f32x4;

__device__ __forceinline__ ushort f2bf(float x) {
    union { __hip_bfloat16 h; ushort u; } cv;
    cv.h = __float2bfloat16(x);
    return cv.u;
}
__device__ __forceinline__ float bf2f(ushort u) {
    union { unsigned int i; float f; } cv; cv.i = ((unsigned int)u) << 16; return cv.f;
}
// swizzles: XOR row-bits into 16B-slot bits -> near-uniform bank coverage
__device__ __forceinline__ int swz256(int row, int cb) { return (row * 256 + cb) ^ ((row & 7) << 4); }
__device__ __forceinline__ int swz128(int row, int cb) { return (row * 128 + cb) ^ ((row & 7) << 4); }
__device__ __forceinline__ size_t trow(int row) { return (size_t)(row % LDIM) * LDIM + row / LDIM; }

// ---------------- weight prep: fp32 [K][N] -> bf16 [N][KP] (zero-padded K) ----------------
__global__ __launch_bounds__(256) void wprep_kernel(ushort* __restrict__ wt,
    const float* emb_w, const float* proj_w,
    const float* rwq, const float* rwk, const float* rwv, const float* rwg, const float* rwo,
    const float* cwq, const float* cwk, const float* cwv, const float* cwg, const float* cwo,
    const float* ffw1, const float* ffw2)
{
    int y = blockIdx.y;
    const float* src; int N, K, KP; size_t off;
    switch (y) {
        case 0:  src = emb_w;  N = 128; K = 36;  KP = 128; off = 0;         break;
        case 1:  src = proj_w; N = 128; K = 128; KP = 128; off = 16384;     break;
        case 2:  src = rwq;    N = 128; K = 128; KP = 128; off = 2*16384;   break;
        case 3:  src = rwk;    N = 128; K = 128; KP = 128; off = 3*16384;   break;
        case 4:  src = rwv;    N = 128; K = 128; KP = 128; off = 4*16384;   break;
        case 5:  src = rwg;    N = 128; K = 128; KP = 128; off = 5*16384;   break;
        case 6:  src = rwo;    N = 128; K = 128; KP = 128; off = 6*16384;   break;
        case 7:  src = cwq;    N = 128; K = 128; KP = 128; off = 7*16384;   break;
        case 8:  src = cwk;    N = 128; K = 128; KP = 128; off = 8*16384;   break;
        case 9:  src = cwv;    N = 128; K = 128; KP = 128; off = 9*16384;   break;
        case 10: src = cwg;    N = 128; K = 128; KP = 128; off = 10*16384;  break;
        case 11: src = cwo;    N = 128; K = 128; KP = 128; off = 11*16384;  break;
        case 12: src = ffw1;   N = 256; K = 128; KP = 128; off = 12*16384;  break;
        default: src = ffw2;   N = 128; K = 256; KP = 256; off = 12*16384 + 32768; break;
    }
    int e = blockIdx.x * 256 + threadIdx.x;
    if (e >= N * KP) return;
    int nn = e / KP, kp = e - nn * KP;
    float v = (kp < K) ? src[(size_t)kp * N + nn] : 0.f;
    wt[off + e] = f2bf(v);
}

// ------- LN + bf16 pack: coalesced read of src row p, write to dst row trans(p) -------
__global__ __launch_bounds__(256) void lnpack_kernel(const float* __restrict__ src,
    ushort* __restrict__ dst, const float* __restrict__ w, const float* __restrict__ b, int trans)
{
    int p = (blockIdx.x << 2) + (threadIdx.x >> 6);
    int lane = threadIdx.x & 63;
    float2 v = *(const float2*)(src + (size_t)p * CDIM + (lane << 1));
    float s  = v.x + v.y;
    float ss = v.x*v.x + v.y*v.y;
    #pragma unroll
    for (int off = 32; off; off >>= 1) { s += __shfl_xor(s, off, 64); ss += __shfl_xor(ss, off, 64); }
    float mean = s * (1.0f/CDIM);
    float var  = ss * (1.0f/CDIM) - mean*mean;
    float rstd = rsqrtf(var + 1e-5f);
    int q = trans ? ((p % LDIM) * LDIM + p / LDIM) : p;
    ushort2 o;
    o.x = f2bf((v.x - mean) * rstd * w[lane<<1]     + b[lane<<1]);
    o.y = f2bf((v.y - mean) * rstd * w[(lane<<1)+1] + b[(lane<<1)+1]);
    *(ushort2*)(dst + (size_t)q * CDIM + (lane << 1)) = o;
}

// ------- bias-attention: coalesced read rbf row p=(a,b); write battn[h, i, j] (trans swaps) -------
__global__ __launch_bounds__(256) void battn_kernel(const float* __restrict__ rbf,
    float* __restrict__ battn, const float* __restrict__ lnw, const float* __restrict__ lnb,
    const float* __restrict__ wb, int trans)
{
    int p = (blockIdx.x << 2) + (threadIdx.x >> 6);
    int lane = threadIdx.x & 63;
    int a = p / LDIM, b2 = p % LDIM;
    float2 v = *(const float2*)(rbf + (size_t)p * CDIM + (lane << 1));
    float s = v.x + v.y, ss = v.x*v.x + v.y*v.y;
    #pragma unroll
    for (int off = 32; off; off >>= 1) { s += __shfl_xor(s, off, 64); ss += __shfl_xor(ss, off, 64); }
    float mean = s*(1.f/CDIM), var = ss*(1.f/CDIM) - mean*mean, rstd = rsqrtf(var + 1e-5f);
    float x0 = (v.x - mean)*rstd*lnw[lane<<1]     + lnb[lane<<1];
    float x1 = (v.y - mean)*rstd*lnw[(lane<<1)+1] + lnb[(lane<<1)+1];
    int c0 = (lane<<1)*HN, c1 = ((lane<<1)+1)*HN;
    float a0 = x0*wb[c0+0] + x1*wb[c1+0];
    float a1 = x0*wb[c0+1] + x1*wb[c1+1];
    float a2 = x0*wb[c0+2] + x1*wb[c1+2];
    float a3 = x0*wb[c0+3] + x1*wb[c1+3];
    #pragma unroll
    for (int off = 32; off; off >>= 1) {
        a0 += __shfl_xor(a0, off, 64); a1 += __shfl_xor(a1, off, 64);
        a2 += __shfl_xor(a2, off, 64); a3 += __shfl_xor(a3, off, 64);
    }
    if (lane == 0) {
        int io = trans ? b2 : a, jo = trans ? a : b2;
        battn[((size_t)0*LDIM + io)*LDIM + jo] = a0;
        battn[((size_t)1*LDIM + io)*LDIM + jo] = a1;
        battn[((size_t)2*LDIM + io)*LDIM + jo] = a2;
        battn[((size_t)3*LDIM + io)*LDIM + jo] = a3;
    }
}

// ------- BK=64 128x128-tile MFMA GEMM. AMODE: 0 fp32, 1 bf16, 2 bf16 gated. -------
// OUTMODE: 0 fp32 natural (+res), 1 bf16 natural, 3 fp32 w/ rtrans/otrans (+res)
// LNOUT: fuse LayerNorm over the 128 output channels (requires N=128, grid.x=1, OUTMODE 0/3):
//        writes out fp32 AND xln bf16 = LN(out) with lnw2/lnb2.
template<int ACT, int AMODE, int OUTMODE, int LNOUT>
__global__ __launch_bounds__(256) void mgemm64(
    const void* __restrict__ Ain, const ushort* __restrict__ Wt,
    const float* __restrict__ bias, const ushort* __restrict__ gmul,
    const float* __restrict__ res, void* __restrict__ Cout,
    const float* __restrict__ lnw2, const float* __restrict__ lnb2, ushort* __restrict__ xln,
    int N, int KP, int lda, float alpha, int rtrans, int otrans)
{
    __shared__ ushort As[128*64];
    __shared__ ushort Ws[128*64];
    int t = threadIdx.x, l = t & 63, wv = t >> 6;
    int m0 = blockIdx.y << 7, n0 = blockIdx.x << 7;
    int wm = (wv >> 1) << 6, wn = (wv & 1) << 6;
    int sr = t >> 1;            // staging row
    int sh = (t & 1) << 5;      // k offset (shorts): 0 or 32
    f32x4 acc[4][4] = {};
    for (int k0 = 0; k0 < KP; k0 += 64) {
        if (k0) __syncthreads();
        if (AMODE == 1) {
            const ushort* ap = (const ushort*)Ain + (size_t)(m0 + sr) * lda + k0 + sh;
            #pragma unroll
            for (int u = 0; u < 4; u++)
                *(int4*)((char*)As + swz128(sr, (sh << 1) + (u << 4))) = *(const int4*)(ap + (u << 3));
        } else if (AMODE == 2) {
            const ushort* ap = (const ushort*)Ain + (size_t)(m0 + sr) * lda + k0 + sh;
            const ushort* gp = gmul + (size_t)(m0 + sr) * lda + k0 + sh;
            #pragma unroll
            for (int u = 0; u < 4; u++) {
                int4 av = *(const int4*)(ap + (u << 3));
                int4 gv = *(const int4*)(gp + (u << 3));
                ushort* au = (ushort*)&av; ushort* gu = (ushort*)&gv;
                short v8[8];
                #pragma unroll
                for (int e = 0; e < 8; e++) v8[e] = (short)f2bf(bf2f(au[e]) * bf2f(gu[e]));
                *(int4*)((char*)As + swz128(sr, (sh << 1) + (u << 4))) = *(int4*)v8;
            }
        } else {
            const float* ap = (const float*)Ain + (size_t)(m0 + sr) * lda;
            #pragma unroll
            for (int u = 0; u < 4; u++) {
                short v8[8];
                #pragma unroll
                for (int e = 0; e < 8; e++) {
                    int c = k0 + sh + (u << 3) + e;
                    v8[e] = (short)f2bf((c < lda) ? ap[c] : 0.f);
                }
                *(int4*)((char*)As + swz128(sr, (sh << 1) + (u << 4))) = *(int4*)v8;
            }
        }
        {
            const ushort* wp2 = Wt + (size_t)(n0 + sr) * KP + k0 + sh;
            #pragma unroll
            for (int u = 0; u < 4; u++)
                *(int4*)((char*)Ws + swz128(sr, (sh << 1) + (u << 4))) = *(const int4*)(wp2 + (u << 3));
        }
        __syncthreads();
        #pragma unroll
        for (int ks = 0; ks < 2; ks++) {
            int kb = (ks << 6) + ((l >> 4) << 4);
            bf16x8 a[4], b[4];
            #pragma unroll
            for (int x = 0; x < 4; x++) {
                a[x] = *(const bf16x8*)((char*)As + swz128(wm + (x << 4) + (l & 15), kb));
                b[x] = *(const bf16x8*)((char*)Ws + swz128(wn + (x << 4) + (l & 15), kb));
            }
            #pragma unroll
            for (int i = 0; i < 4; i++)
            #pragma unroll
            for (int j = 0; j < 4; j++)
                acc[i][j] = __builtin_amdgcn_mfma_f32_16x16x32_bf16(a[i], b[j], acc[i][j], 0, 0, 0);
        }
    }
    if (LNOUT) {
        // finalize o = acc*alpha + bias + res into acc
        #pragma unroll
        for (int mf = 0; mf < 4; mf++)
        #pragma unroll
        for (int nf = 0; nf < 4; nf++) {
            int col  = wn + (nf << 4) + (l & 15);
            int row0 = m0 + wm + (mf << 4) + ((l >> 4) << 2);
            float bb = bias ? bias[col] : 0.f;
            #pragma unroll
            for (int r = 0; r < 4; r++) {
                int row = row0 + r;
                size_t rrow = rtrans ? trow(row) : (size_t)row;
                acc[mf][nf][r] = acc[mf][nf][r] * alpha + bb + (res ? res[rrow * CDIM + col] : 0.f);
            }
        }
        // per-row partial sums over this lane's 4 nf values
        float ps[4][4], pq[4][4];
        #pragma unroll
        for (int mf = 0; mf < 4; mf++)
        #pragma unroll
        for (int r = 0; r < 4; r++) {
            float s = 0.f, q = 0.f;
            #pragma unroll
            for (int nf = 0; nf < 4; nf++) { float v = acc[mf][nf][r]; s += v; q += v * v; }
            ps[mf][r] = s; pq[mf][r] = q;
        }
        #pragma unroll
        for (int off = 1; off < 16; off <<= 1)
        #pragma unroll
        for (int mf = 0; mf < 4; mf++)
        #pragma unroll
        for (int r = 0; r < 4; r++) {
            ps[mf][r] += __shfl_xor(ps[mf][r], off, 64);
            pq[mf][r] += __shfl_xor(pq[mf][r], off, 64);
        }
        __syncthreads();                 // staging LDS now reusable
        float* lnbuf = (float*)As;       // [2][128][2]
        if ((l & 15) == 0) {
            #pragma unroll
            for (int mf = 0; mf < 4; mf++)
            #pragma unroll
            for (int r = 0; r < 4; r++) {
                int rl = wm + (mf << 4) + ((l >> 4) << 2) + r;
                lnbuf[(((wv & 1) << 7) + rl) * 2 + 0] = ps[mf][r];
                lnbuf[(((wv & 1) << 7) + rl) * 2 + 1] = pq[mf][r];
            }
        }
        __syncthreads();
        #pragma unroll
        for (int mf = 0; mf < 4; mf++)
        #pragma unroll
        for (int nf = 0; nf < 4; nf++) {
            int col  = wn + (nf << 4) + (l & 15);
            int row0 = m0 + wm + (mf << 4) + ((l >> 4) << 2);
            float lw = lnw2[col], lb = lnb2[col];
            #pragma unroll
            for (int r = 0; r < 4; r++) {
                int row = row0 + r;
                int rl  = wm + (mf << 4) + ((l >> 4) << 2) + r;
                float s  = lnbuf[rl * 2 + 0] + lnbuf[(256 + rl * 2) + 0];
                float q  = lnbuf[rl * 2 + 1] + lnbuf[(256 + rl * 2) + 1];
                float mean = s * (1.f/CDIM);
                float var  = q * (1.f/CDIM) - mean * mean;
                float rstd = rsqrtf(var + 1e-5f);
                float o = acc[mf][nf][r];
                size_t orow = otrans ? trow(row) : (size_t)row;
                ((float*)Cout)[orow * CDIM + col] = o;
                xln[orow * CDIM + col] = f2bf((o - mean) * rstd * lw + lb);
            }
        }
    } else {
        #pragma unroll
        for (int mf = 0; mf < 4; mf++)
        #pragma unroll
        for (int nf = 0; nf < 4; nf++) {
            int col  = n0 + wn + (nf << 4) + (l & 15);
            int row0 = m0 + wm + (mf << 4) + ((l >> 4) << 2);
            float bb = bias ? bias[col] : 0.f;
            #pragma unroll
            for (int r = 0; r < 4; r++) {
                int row = row0 + r;
                float v = acc[mf][nf][r] * alpha + bb;
                if (ACT == 1) v = fmaxf(v, 0.f);
                if (ACT == 2) v = 1.f / (1.f + __expf(-v));
                if (OUTMODE == 0) {
                    float o = v + (res ? res[(size_t)row * N + col] : 0.f);
                    ((float*)Cout)[(size_t)row * N + col] = o;
                } else if (OUTMODE == 1) {
                    ((ushort*)Cout)[(size_t)row * N + col] = f2bf(v);
                } else {
                    size_t orow = otrans ? trow(row) : (size_t)row;
                    size_t rrow = rtrans ? trow(row) : (size_t)row;
                    float o = v + (res ? res[rrow * N + col] : 0.f);
                    ((float*)Cout)[orow * N + col] = o;
                }
            }
        }
    }
}

// ------- q,k,v in one kernel: A-tile staged ONCE, loop 3 weight tiles. -------
__global__ __launch_bounds__(256) void qkv3_gemm(
    const ushort* __restrict__ A, const ushort* __restrict__ wt3,
    ushort* __restrict__ qo, ushort* __restrict__ ko, ushort* __restrict__ vt,
    float scale_q, float scale_k)
{
    __shared__ ushort As[128*128];
    __shared__ ushort Ws[128*128];
    int t = threadIdx.x, l = t & 63, wv = t >> 6;
    int m0 = blockIdx.x << 7;
    int wm = (wv >> 1) << 6, wn = (wv & 1) << 6;
    int sr = t >> 1, scb = (t & 1) << 7;
    {
        const ushort* ap = A + (size_t)(m0 + sr) * CDIM + (scb >> 1);
        #pragma unroll
        for (int u = 0; u < 8; u++)
            *(int4*)((char*)As + swz256(sr, scb + (u << 4))) = *(const int4*)(ap + (u << 3));
    }
    for (int comp = 0; comp < 3; comp++) {
        if (comp) __syncthreads();
        const ushort* wp2 = wt3 + (size_t)comp * 16384 + (size_t)sr * CDIM + (scb >> 1);
        #pragma unroll
        for (int u = 0; u < 8; u++)
            *(int4*)((char*)Ws + swz256(sr, scb + (u << 4))) = *(const int4*)(wp2 + (u << 3));
        __syncthreads();
        f32x4 acc[4][4] = {};
        #pragma unroll
        for (int ks = 0; ks < 4; ks++) {
            int kb = (ks << 6) + ((l >> 4) << 4);
            bf16x8 a[4], b[4];
            #pragma unroll
            for (int x = 0; x < 4; x++) {
                a[x] = *(const bf16x8*)((char*)As + swz256(wm + (x << 4) + (l & 15), kb));
                b[x] = *(const bf16x8*)((char*)Ws + swz256(wn + (x << 4) + (l & 15), kb));
            }
            #pragma unroll
            for (int i = 0; i < 4; i++)
            #pragma unroll
            for (int j = 0; j < 4; j++)
                acc[i][j] = __builtin_amdgcn_mfma_f32_16x16x32_bf16(a[i], b[j], acc[i][j], 0, 0, 0);
        }
        #pragma unroll
        for (int mf = 0; mf < 4; mf++)
        #pragma unroll
        for (int nf = 0; nf < 4; nf++) {
            int col  = wn + (nf << 4) + (l & 15);
            int row0 = m0 + wm + (mf << 4) + ((l >> 4) << 2);
            if (comp == 0) {
                #pragma unroll
                for (int r = 0; r < 4; r++)
                    qo[(size_t)(row0 + r) * CDIM + col] = f2bf(acc[mf][nf][r] * scale_q);
            } else if (comp == 1) {
                #pragma unroll
                for (int r = 0; r < 4; r++)
                    ko[(size_t)(row0 + r) * CDIM + col] = f2bf(acc[mf][nf][r] * scale_k);
            } else {
                ushort4 pk;
                #pragma unroll
                for (int r = 0; r < 4; r++) ((ushort*)&pk)[r] = f2bf(acc[mf][nf][r]);
                int n = row0 / LDIM, j = row0 % LDIM;
                *(ushort4*)&vt[((size_t)(col >> 5) * 12288 + (size_t)n * 32 + (col & 31)) * 384 + j] = pk;
            }
        }
    }
}

// ------- tied scores: partial[cz,h,i,j] = sum_{n in chunk} q[n,i,h,:].k[n,j,h,:] -------
__global__ __launch_bounds__(256) void score128(const ushort* __restrict__ Q,
    const ushort* __restrict__ Kb, float* __restrict__ partial)
{
    __shared__ ushort As[128*128];
    __shared__ ushort Bs[128*128];
    int t = threadIdx.x, l = t & 63, wv = t >> 6;
    int ti = blockIdx.x / 3, tj = blockIdx.x % 3;
    int h = blockIdx.y, cz = blockIdx.z;
    int i0 = ti << 7, j0 = tj << 7;
    int wm = (wv >> 1) << 6, wn = (wv & 1) << 6;
    int sr = t >> 1, half = t & 1;
    f32x4 acc[4][4] = {};
    for (int it = 0; it < 12; it++) {
        if (it) __syncthreads();
        int nb = cz * 48 + (it << 2);
        #pragma unroll
        for (int e = 0; e < 2; e++) {
            int nq = (half << 1) + e;
            const ushort* qp = Q  + ((size_t)(nb + nq) * LDIM + i0 + sr) * CDIM + (h << 5);
            const ushort* kp = Kb + ((size_t)(nb + nq) * LDIM + j0 + sr) * CDIM + (h << 5);
            *(int4*)((char*)As + swz256(sr, (nq << 6) +  0)) = *(const int4*)qp;
            *(int4*)((char*)As + swz256(sr, (nq << 6) + 16)) = *(const int4*)(qp + 8);
            *(int4*)((char*)As + swz256(sr, (nq << 6) + 32)) = *(const int4*)(qp + 16);
            *(int4*)((char*)As + swz256(sr, (nq << 6) + 48)) = *(const int4*)(qp + 24);
            *(int4*)((char*)Bs + swz256(sr, (nq << 6) +  0)) = *(const int4*)kp;
            *(int4*)((char*)Bs + swz256(sr, (nq << 6) + 16)) = *(const int4*)(kp + 8);
            *(int4*)((char*)Bs + swz256(sr, (nq << 6) + 32)) = *(const int4*)(kp + 16);
            *(int4*)((char*)Bs + swz256(sr, (nq << 6) + 48)) = *(const int4*)(kp + 24);
        }
        __syncthreads();
        #pragma unroll
        for (int ks = 0; ks < 4; ks++) {
            int kb = (ks << 6) + ((l >> 4) << 4);
            bf16x8 a[4], b[4];
            #pragma unroll
            for (int x = 0; x < 4; x++) {
                a[x] = *(const bf16x8*)((char*)As + swz256(wm + (x << 4) + (l & 15), kb));
                b[x] = *(const bf16x8*)((char*)Bs + swz256(wn + (x << 4) + (l & 15), kb));
            }
            #pragma unroll
            for (int i = 0; i < 4; i++)
            #pragma unroll
            for (int j = 0; j < 4; j++)
                acc[i][j] = __builtin_amdgcn_mfma_f32_16x16x32_bf16(a[i], b[j], acc[i][j], 0, 0, 0);
        }
    }
    #pragma unroll
    for (int mf = 0; mf < 4; mf++)
    #pragma unroll
    for (int nf = 0; nf < 4; nf++) {
        int j = j0 + wn + (nf << 4) + (l & 15);
        int i = i0 + wm + (mf << 4) + ((l >> 4) << 2);
        #pragma unroll
        for (int r = 0; r < 4; r++)
            partial[((size_t)(cz*HN + h)*LDIM + i + r)*LDIM + j] = acc[mf][nf][r];
    }
}

// ---------------- softmax over j (chunk reduce + bias) -> bf16 ----------------
__global__ __launch_bounds__(64) void softmax_kernel(
    const float* __restrict__ partial, const float* __restrict__ battn, ushort* __restrict__ attn)
{
    int hi = blockIdx.x;
    int l = threadIdx.x;
    float s[6];
    #pragma unroll
    for (int u = 0; u < 6; u++) {
        size_t idx = (size_t)hi * LDIM + l + (u << 6);
        float v = battn[idx];
        #pragma unroll
        for (int c = 0; c < NCHUNK; c++) v += partial[(size_t)c * HN * LL + idx];
        s[u] = v;
    }
    float m = s[0];
    #pragma unroll
    for (int u = 1; u < 6; u++) m = fmaxf(m, s[u]);
    #pragma unroll
    for (int off = 32; off; off >>= 1) m = fmaxf(m, __shfl_xor(m, off, 64));
    float sum = 0.f;
    #pragma unroll
    for (int u = 0; u < 6; u++) { s[u] = __expf(s[u] - m); sum += s[u]; }
    #pragma unroll
    for (int off = 32; off; off >>= 1) sum += __shfl_xor(sum, off, 64);
    float inv = 1.f / sum;
    #pragma unroll
    for (int u = 0; u < 6; u++) attn[(size_t)hi * LDIM + l + (u << 6)] = f2bf(s[u] * inv);
}

// ------- PV as per-head GEMM (BK=64): pvout[(n,i),h*32+d] = sum_j attn[h,i,j]*vt[h][(n,d)][j] -------
__global__ __launch_bounds__(256) void pvg_gemm(const ushort* __restrict__ attn,
    const ushort* __restrict__ vt, ushort* __restrict__ pvout)
{
    __shared__ ushort As[128*64];
    __shared__ ushort Ws[128*64];
    int t = threadIdx.x, l = t & 63, wv = t >> 6;
    int n0 = blockIdx.x << 7;
    int i0 = blockIdx.y << 7;
    int h  = blockIdx.z;
    const ushort* abase = attn + (size_t)h * LL;
    const ushort* bbase = vt + (size_t)h * VTPLANE;
    int wm = (wv >> 1) << 6, wn = (wv & 1) << 6;
    int sr = t >> 1, sh = (t & 1) << 5;
    f32x4 acc[4][4] = {};
    for (int k0 = 0; k0 < LDIM; k0 += 64) {
        if (k0) __syncthreads();
        {
            const ushort* ap = abase + (size_t)(i0 + sr) * LDIM + k0 + sh;
            const ushort* bp = bbase + (size_t)(n0 + sr) * LDIM + k0 + sh;
            #pragma unroll
            for (int u = 0; u < 4; u++) {
                *(int4*)((char*)As + swz128(sr, (sh << 1) + (u << 4))) = *(const int4*)(ap + (u << 3));
                *(int4*)((char*)Ws + swz128(sr, (sh << 1) + (u << 4))) = *(const int4*)(bp + (u << 3));
            }
        }
        __syncthreads();
        #pragma unroll
        for (int ks = 0; ks < 2; ks++) {
            int kb = (ks << 6) + ((l >> 4) << 4);
            bf16x8 a[4], b[4];
            #pragma unroll
            for (int x = 0; x < 4; x++) {
                a[x] = *(const bf16x8*)((char*)As + swz128(wm + (x << 4) + (l & 15), kb));
                b[x] = *(const bf16x8*)((char*)Ws + swz128(wn + (x << 4) + (l & 15), kb));
            }
            #pragma unroll
            for (int i = 0; i < 4; i++)
            #pragma unroll
            for (int j = 0; j < 4; j++)
                acc[i][j] = __builtin_amdgcn_mfma_f32_16x16x32_bf16(a[i], b[j], acc[i][j], 0, 0, 0);
        }
    }
    #pragma unroll
    for (int mf = 0; mf < 4; mf++)
    #pragma unroll
    for (int nf = 0; nf < 4; nf++) {
        int col  = n0 + wn + (nf << 4) + (l & 15);
        int row0 = i0 + wm + (mf << 4) + ((l >> 4) << 2);
        int n = col >> 5, d = col & 31;
        #pragma unroll
        for (int r = 0; r < 4; r++) {
            int i = row0 + r;
            pvout[((size_t)n * LDIM + i) * CDIM + (h << 5) + d] = f2bf(acc[mf][nf][r]);
        }
    }
}

extern "C" void kernel_launch(void* const* d_in, const int* in_sizes, int n_in,
                              void* d_out, int out_size, void* d_ws, size_t ws_size,
                              hipStream_t stream)
{
    const float* pair     = (const float*)d_in[0];
    const float* rbf_feat = (const float*)d_in[1];
    const float* emb_b    = (const float*)d_in[3];
    const float* proj_b   = (const float*)d_in[5];
    const float* ff_ln_w  = (const float*)d_in[30];
    const float* ff_ln_b  = (const float*)d_in[31];
    const float* ff_b1    = (const float*)d_in[33];
    const float* ff_b2    = (const float*)d_in[35];
    float* out = (float*)d_out;

    ushort* R0 = (ushort*)d_ws;              // q -> pvout
    ushort* R1 = R0 + (size_t)LL*CDIM;       // k -> g
    ushort* R2 = R1 + (size_t)LL*CDIM;       // vt [h][(n,d)][j]
    ushort* R3 = R2 + (size_t)LL*CDIM;       // xln (LN bf16)
    float*  partialb = (float*)(R3 + (size_t)LL*CDIM);
    float*  battn_r  = partialb + (size_t)NCHUNK*HN*LL;
    float*  battn_c  = battn_r  + (size_t)HN*LL;
    ushort* attn_bf  = (ushort*)(battn_c + (size_t)HN*LL);
    ushort* wt       = attn_bf + (size_t)HN*LL;

    size_t need_bytes = (size_t)4*LL*CDIM*2 + ((size_t)NCHUNK*HN*LL + 2*(size_t)HN*LL)*4
                      + (size_t)HN*LL*2 + (size_t)262144*2;
    if (ws_size < need_bytes) return;

    const size_t WS = 16384;
    ushort* wt_emb  = wt;
    ushort* wt_proj = wt + WS;
    ushort* wt_ff1  = wt + 12*WS;
    ushort* wt_ff2  = wt + 12*WS + 32768;

    const float SCALE = 0.17677669529663687f;  // 32^-0.5

    wprep_kernel<<<dim3(128, 14), 256, 0, stream>>>(wt,
        (const float*)d_in[2], (const float*)d_in[4],
        (const float*)d_in[10], (const float*)d_in[11], (const float*)d_in[12],
        (const float*)d_in[14], (const float*)d_in[16],
        (const float*)d_in[22], (const float*)d_in[23], (const float*)d_in[24],
        (const float*)d_in[26], (const float*)d_in[28],
        (const float*)d_in[32], (const float*)d_in[34]);

    // rbf = relu(rbf_feat@emb+eb)@proj+pb : hidden bf16 -> R3; rbf fp32 spans R0+R1
    mgemm64<1,0,1,0><<<dim3(1,1152), 256, 0, stream>>>(rbf_feat, wt_emb, emb_b, nullptr, nullptr, R3,
        nullptr, nullptr, nullptr, 128, 128, 36, 1.f, 0, 0);
    mgemm64<0,1,0,0><<<dim3(1,1152), 256, 0, stream>>>(R3, wt_proj, proj_b, nullptr, nullptr, (float*)R0,
        nullptr, nullptr, nullptr, 128, 128, 128, 1.f, 0, 0);
    battn_kernel<<<LL/4, 256, 0, stream>>>((const float*)R0, battn_r,
        (const float*)d_in[8],  (const float*)d_in[9],  (const float*)d_in[13], 1);
    battn_kernel<<<LL/4, 256, 0, stream>>>((const float*)R0, battn_c,
        (const float*)d_in[20], (const float*)d_in[21], (const float*)d_in[25], 0);

    // row-pass xln (transposed frame) from the input pair
    lnpack_kernel<<<LL/4, 256, 0, stream>>>(pair, R3, (const float*)d_in[6], (const float*)d_in[7], 1);

    for (int pass = 0; pass < 2; pass++) {
        const float* const* wp = (const float* const*)(d_in + (pass ? 18 : 6));
        int trans = pass ? 0 : 1;
        const float* P = pass ? (const float*)out : pair;
        const float* battnb = pass ? battn_c : battn_r;
        int ws0 = pass ? 7 : 2;   // wq slot; k,v,g,o follow
        // next LN params: col pass uses c_lnp (fused into row wo); FFN uses ff_ln (fused into col wo)
        const float* nlw = pass ? ff_ln_w : (const float*)d_in[18];
        const float* nlb = pass ? ff_ln_b : (const float*)d_in[19];
        qkv3_gemm<<<1152, 256, 0, stream>>>(R3, wt + ws0*WS, R0, R1, R2, SCALE, 1.f/LDIM);
        score128<<<dim3(9, HN, NCHUNK), 256, 0, stream>>>(R0, R1, partialb);
        softmax_kernel<<<HN*LDIM, 64, 0, stream>>>(partialb, battnb, attn_bf);
        // g = sigmoid(xln@wg+bg) -> R1 (k dead after score)
        mgemm64<2,1,1,0><<<dim3(1,1152), 256, 0, stream>>>(R3, wt + (ws0+3)*WS, wp[9], nullptr, nullptr, R1,
            nullptr, nullptr, nullptr, 128, 128, 128, 1.f, 0, 0);
        // pvout -> R0 (q dead)
        pvg_gemm<<<dim3(96, 3, 4), 256, 0, stream>>>(attn_bf, R2, R0);
        // pair_out = residual + (g .* pv)@wo + bo ; fused: xln = LN(pair_out) for the NEXT stage -> R3
        mgemm64<0,2,3,1><<<dim3(1,1152), 256, 0, stream>>>(R0, wt + (ws0+4)*WS, wp[11], R1, P, out,
            nlw, nlb, R3, 128, 128, 128, 1.f, trans, trans);
    }

    // FFN: out += relu(xln@w1+b1)@w2+b2  (h1 bf16 [LL][256] spans R0+R1)
    mgemm64<1,1,1,0><<<dim3(2,1152), 256, 0, stream>>>(R3, wt_ff1, ff_b1, nullptr, nullptr, R0,
        nullptr, nullptr, nullptr, 256, 128, 128, 1.f, 0, 0);
    mgemm64<0,1,0,0><<<dim3(1,1152), 256, 0, stream>>>(R0, wt_ff2, ff_b2, nullptr, out, out,
        nullptr, nullptr, nullptr, 128, 256, 256, 1.f, 0, 0);
}